// Round 5
// baseline (1240.472 us; speedup 1.0000x reference)
//
#include <hip/hip_runtime.h>
#include <math.h>

// ---------------- problem constants ----------------
#define DD   256
#define NHH  8
#define HDIM 32
#define NLV  4
#define NPT  4
#define BSZ  4
#define NQQ  300
#define NKK  17
#define LQQ  (NQQ*NKK)      // 5100
#define NROW (BSZ*LQQ)      // 20400
#define LVV  11253
#define FFD  1024

typedef __attribute__((ext_vector_type(8))) short bf16x8;
typedef __attribute__((ext_vector_type(4))) float f32x4;

__device__ __forceinline__ unsigned short f2bf(float f) {
    unsigned int u = __float_as_uint(f);
    u = u + 0x7FFFu + ((u >> 16) & 1u);   // round-to-nearest-even
    return (unsigned short)(u >> 16);
}

// ---------------- elementwise add (float4) ----------------
__global__ __launch_bounds__(256) void k_add(const float4* __restrict__ a,
                                             const float4* __restrict__ b,
                                             float4* __restrict__ o, int n4) {
    int i = blockIdx.x * 256 + threadIdx.x;
    if (i < n4) {
        float4 x = a[i], y = b[i];
        o[i] = make_float4(x.x + y.x, x.y + y.y, x.z + y.z, x.w + y.w);
    }
}

// ---------------- concat [Q | T2] -> 512-wide ----------------
__global__ __launch_bounds__(256) void k_concat(const float4* __restrict__ a,
                                                const float4* __restrict__ b,
                                                float4* __restrict__ o, int rows) {
    int i = blockIdx.x * 256 + threadIdx.x;  // over rows*128 float4s
    if (i >= rows * 128) return;
    int r = i >> 7, c = i & 127;
    o[i] = (c < 64) ? a[(size_t)r * 64 + c] : b[(size_t)r * 64 + (c - 64)];
}

// ---------------- MFMA GEMM: C = act(A @ B^T + bias) ----------------
// A: M x K fp32 row-major; B: N x K fp32 row-major (torch weight); C: M x N fp32.
// Tile 64x64, BK=32, 4 waves (wave w owns rows w*16..w*16+15, all 64 cols).
// Requires: N % 64 == 0, K % 32 == 0. M arbitrary (guards).
// ACT: 0 none, 1 relu, 2 sigmoid
template<int ACT>
__global__ __launch_bounds__(256) void k_gemm_mfma(const float* __restrict__ A,
                                                   const float* __restrict__ B,
                                                   const float* __restrict__ bias,
                                                   float* __restrict__ C,
                                                   int M, int N, int K) {
    // rows padded to 40 ushorts (80 B): 16B-aligned b128 reads, bank spread row*20%32 (<=2-way)
    __shared__ unsigned short As[64][40];
    __shared__ unsigned short Bs[64][40];
    int t = threadIdx.x;
    int lane = t & 63, w = t >> 6;
    int l16 = lane & 15, hi = lane >> 4;
    int row0 = blockIdx.x * 64, col0 = blockIdx.y * 64;
    int srow = t >> 2;            // 0..63  (staging row)
    int scol = (t & 3) * 8;       // 0,8,16,24 (staging col, 8 elems)

    f32x4 acc[4];
    #pragma unroll
    for (int i = 0; i < 4; i++) acc[i] = (f32x4){0.f, 0.f, 0.f, 0.f};

    for (int k0 = 0; k0 < K; k0 += 32) {
        // ---- stage A tile (64 x 32) fp32 -> bf16 ----
        {
            float v[8];
            int gr = row0 + srow;
            if (gr < M) {
                const float4* p = (const float4*)(A + (size_t)gr * K + k0 + scol);
                float4 x = p[0], y = p[1];
                v[0] = x.x; v[1] = x.y; v[2] = x.z; v[3] = x.w;
                v[4] = y.x; v[5] = y.y; v[6] = y.z; v[7] = y.w;
            } else {
                #pragma unroll
                for (int i = 0; i < 8; i++) v[i] = 0.f;
            }
            bf16x8 h;
            #pragma unroll
            for (int i = 0; i < 8; i++) h[i] = (short)f2bf(v[i]);
            *(bf16x8*)&As[srow][scol] = h;
        }
        // ---- stage B tile (64 x 32) fp32 -> bf16 ----
        {
            float v[8];
            int gb = col0 + srow;   // always < N (N % 64 == 0)
            const float4* p = (const float4*)(B + (size_t)gb * K + k0 + scol);
            float4 x = p[0], y = p[1];
            v[0] = x.x; v[1] = x.y; v[2] = x.z; v[3] = x.w;
            v[4] = y.x; v[5] = y.y; v[6] = y.z; v[7] = y.w;
            bf16x8 h;
            #pragma unroll
            for (int i = 0; i < 8; i++) h[i] = (short)f2bf(v[i]);
            *(bf16x8*)&Bs[srow][scol] = h;
        }
        __syncthreads();
        // ---- fragments + MFMA ----
        // A operand: A[i][k], i = lane%16 (abs row w*16+l16), k = 8*(lane/16)+reg
        bf16x8 af = *(const bf16x8*)&As[(w << 4) + l16][hi * 8];
        #pragma unroll
        for (int nt = 0; nt < 4; nt++) {
            // B operand: B[k][j], j = lane%16 -> weight row col0+nt*16+l16, k = 8*hi+reg
            bf16x8 bf = *(const bf16x8*)&Bs[nt * 16 + l16][hi * 8];
            acc[nt] = __builtin_amdgcn_mfma_f32_16x16x32_bf16(af, bf, acc[nt], 0, 0, 0);
        }
        __syncthreads();
    }
    // ---- epilogue: D[i][j]: j = lane%16, i = 4*(lane/16)+reg ----
    #pragma unroll
    for (int nt = 0; nt < 4; nt++) {
        int col = col0 + nt * 16 + l16;
        float bv = bias[col];
        #pragma unroll
        for (int r = 0; r < 4; r++) {
            int row = row0 + (w << 4) + (hi << 2) + r;
            if (row < M) {
                float v = acc[nt][r] + bv;
                if (ACT == 1) v = fmaxf(v, 0.f);
                else if (ACT == 2) v = 1.f / (1.f + __expf(-v));
                C[(size_t)row * N + col] = v;
            }
        }
    }
}

// ---------------- fp32 fallback GEMM (kept for quick revert; unused) ----------------
template<int ACT>
__global__ __launch_bounds__(256) void k_gemm(const float* __restrict__ A,
                                              const float* __restrict__ B,
                                              const float* __restrict__ bias,
                                              float* __restrict__ C,
                                              int M, int N, int K) {
    __shared__ float As[16][64];
    __shared__ float Bs[16][64];
    int tid = threadIdx.x;
    int tx = tid & 15, ty = tid >> 4;
    int row0 = blockIdx.x * 64, col0 = blockIdx.y * 64;
    float acc[4][4] = {};
    for (int k0 = 0; k0 < K; k0 += 16) {
        int kk = tid & 15;
        int rr = tid >> 4;
        #pragma unroll
        for (int i = 0; i < 4; i++) {
            int r = rr + i * 16;
            int gr = row0 + r;
            As[kk][r] = (gr < M) ? A[(size_t)gr * K + k0 + kk] : 0.f;
            int gc = col0 + r;
            Bs[kk][r] = (gc < N) ? B[(size_t)gc * K + k0 + kk] : 0.f;
        }
        __syncthreads();
        #pragma unroll
        for (int k = 0; k < 16; k++) {
            float av[4], bv[4];
            #pragma unroll
            for (int i = 0; i < 4; i++) av[i] = As[k][ty * 4 + i];
            #pragma unroll
            for (int j = 0; j < 4; j++) bv[j] = Bs[k][tx * 4 + j];
            #pragma unroll
            for (int i = 0; i < 4; i++)
                #pragma unroll
                for (int j = 0; j < 4; j++)
                    acc[i][j] += av[i] * bv[j];
        }
        __syncthreads();
    }
    #pragma unroll
    for (int i = 0; i < 4; i++) {
        int r = row0 + ty * 4 + i;
        if (r >= M) continue;
        #pragma unroll
        for (int j = 0; j < 4; j++) {
            int c = col0 + tx * 4 + j;
            if (c >= N) continue;
            float v = acc[i][j] + bias[c];
            if (ACT == 1) v = fmaxf(v, 0.f);
            else if (ACT == 2) v = 1.f / (1.f + __expf(-v));
            C[(size_t)r * N + c] = v;
        }
    }
}

// ---------------- LayerNorm(a + b) * g + beta, one wave per row ----------------
__global__ __launch_bounds__(256) void k_ln_res(const float* __restrict__ A,
                                                const float* __restrict__ Bp,
                                                const float* __restrict__ g,
                                                const float* __restrict__ be,
                                                float* __restrict__ O, int M) {
    int row = blockIdx.x * 4 + (threadIdx.x >> 6);
    int lane = threadIdx.x & 63;
    if (row >= M) return;
    float4 a = ((const float4*)A)[(size_t)row * 64 + lane];
    float4 b = ((const float4*)Bp)[(size_t)row * 64 + lane];
    float x0 = a.x + b.x, x1 = a.y + b.y, x2 = a.z + b.z, x3 = a.w + b.w;
    float s = x0 + x1 + x2 + x3;
    float sq = x0 * x0 + x1 * x1 + x2 * x2 + x3 * x3;
    #pragma unroll
    for (int o = 32; o; o >>= 1) { s += __shfl_xor(s, o); sq += __shfl_xor(sq, o); }
    float mean = s * (1.f / 256.f);
    float var = sq * (1.f / 256.f) - mean * mean;
    float rs = rsqrtf(var + 1e-5f);
    float4 gg = ((const float4*)g)[lane];
    float4 bb = ((const float4*)be)[lane];
    float4 o4;
    o4.x = (x0 - mean) * rs * gg.x + bb.x;
    o4.y = (x1 - mean) * rs * gg.y + bb.y;
    o4.z = (x2 - mean) * rs * gg.z + bb.z;
    o4.w = (x3 - mean) * rs * gg.w + bb.w;
    ((float4*)O)[(size_t)row * 64 + lane] = o4;
}

// ---------------- LayerNorm(g1*Q + g2*T2) * g + beta ----------------
__global__ __launch_bounds__(256) void k_ln_gate(const float* __restrict__ G,
                                                 const float* __restrict__ Q,
                                                 const float* __restrict__ T2,
                                                 const float* __restrict__ g,
                                                 const float* __restrict__ be,
                                                 float* __restrict__ O, int M) {
    int row = blockIdx.x * 4 + (threadIdx.x >> 6);
    int lane = threadIdx.x & 63;
    if (row >= M) return;
    float4 g1 = ((const float4*)G)[(size_t)row * 128 + lane];
    float4 g2 = ((const float4*)G)[(size_t)row * 128 + 64 + lane];
    float4 q = ((const float4*)Q)[(size_t)row * 64 + lane];
    float4 t = ((const float4*)T2)[(size_t)row * 64 + lane];
    float x0 = g1.x * q.x + g2.x * t.x;
    float x1 = g1.y * q.y + g2.y * t.y;
    float x2 = g1.z * q.z + g2.z * t.z;
    float x3 = g1.w * q.w + g2.w * t.w;
    float s = x0 + x1 + x2 + x3;
    float sq = x0 * x0 + x1 * x1 + x2 * x2 + x3 * x3;
    #pragma unroll
    for (int o = 32; o; o >>= 1) { s += __shfl_xor(s, o); sq += __shfl_xor(sq, o); }
    float mean = s * (1.f / 256.f);
    float var = sq * (1.f / 256.f) - mean * mean;
    float rs = rsqrtf(var + 1e-5f);
    float4 gg = ((const float4*)g)[lane];
    float4 bb = ((const float4*)be)[lane];
    float4 o4;
    o4.x = (x0 - mean) * rs * gg.x + bb.x;
    o4.y = (x1 - mean) * rs * gg.y + bb.y;
    o4.z = (x2 - mean) * rs * gg.z + bb.z;
    o4.w = (x3 - mean) * rs * gg.w + bb.w;
    ((float4*)O)[(size_t)row * 64 + lane] = o4;
}

// ---------------- within-group attention: seq len 17, one wave per (seq,head) ----------------
__global__ __launch_bounds__(64) void k_wattn(const float* __restrict__ QKV,
                                              float* __restrict__ AO) {
    int unit = blockIdx.x;          // (seq*8 + h), seq in [0,1200)
    int h = unit & 7;
    int sqc = unit >> 3;
    int lane = threadIdx.x;
    __shared__ float q[17][32], kk[17][32], vv[17][32], sc[17][17];
    for (int idx = lane; idx < 17 * 32; idx += 64) {
        int r = idx >> 5, c = idx & 31;
        const float* base = QKV + (size_t)(sqc * 17 + r) * 768 + h * 32 + c;
        q[r][c] = base[0];
        kk[r][c] = base[256];
        vv[r][c] = base[512];
    }
    __syncthreads();
    const float scale = 0.17677669529663687f;  // 1/sqrt(32)
    for (int idx = lane; idx < 289; idx += 64) {
        int i = idx / 17, j = idx % 17;
        float d = 0.f;
        #pragma unroll
        for (int c = 0; c < 32; c++) d += q[i][c] * kk[j][c];
        sc[i][j] = d * scale;
    }
    __syncthreads();
    if (lane < 17) {
        float mm = -1e30f;
        for (int j = 0; j < 17; j++) mm = fmaxf(mm, sc[lane][j]);
        float ss = 0.f;
        for (int j = 0; j < 17; j++) { float e = __expf(sc[lane][j] - mm); sc[lane][j] = e; ss += e; }
        float iv = 1.f / ss;
        for (int j = 0; j < 17; j++) sc[lane][j] *= iv;
    }
    __syncthreads();
    for (int idx = lane; idx < 17 * 32; idx += 64) {
        int i = idx >> 5, c = idx & 31;
        float o = 0.f;
        #pragma unroll
        for (int j = 0; j < 17; j++) o += sc[i][j] * vv[j][c];
        AO[(size_t)(sqc * 17 + i) * 256 + h * 32 + c] = o;
    }
}

// ---------------- across-group attention: seq len 300, flash-style ----------------
// grid = BSZ*17*8 units; block = 320 threads (one thread = one query row)
__global__ __launch_bounds__(320) void k_acattn(const float* __restrict__ QKV,
                                                float* __restrict__ AO) {
    __shared__ float Ks[100][32];
    __shared__ float Vs[100][32];
    int unit = blockIdx.x;
    int h = unit & 7;
    int bk = unit >> 3;
    int kslot = bk % 17;
    int b = bk / 17;
    int tid = threadIdx.x;
    const float scale = 0.17677669529663687f;
    float qr[32], acc[32];
    float mx = -1e30f, l = 0.f;
    bool act = tid < 300;
    if (act) {
        const float* qp = QKV + ((size_t)(b * 300 + tid) * 17 + kslot) * 768 + h * 32;
        #pragma unroll
        for (int c = 0; c < 32; c++) { qr[c] = qp[c] * scale; acc[c] = 0.f; }
    }
    for (int j0 = 0; j0 < 300; j0 += 100) {
        __syncthreads();
        for (int idx = tid; idx < 100 * 32; idx += 320) {
            int qq = idx >> 5, c = idx & 31;
            const float* base = QKV + ((size_t)(b * 300 + j0 + qq) * 17 + kslot) * 768 + h * 32 + c;
            Ks[qq][c] = base[256];
            Vs[qq][c] = base[512];
        }
        __syncthreads();
        if (act) {
            for (int j = 0; j < 100; j++) {
                float s = 0.f;
                #pragma unroll
                for (int c = 0; c < 32; c++) s += qr[c] * Ks[j][c];
                float mn = fmaxf(mx, s);
                float corr = __expf(mx - mn);
                float e = __expf(s - mn);
                l = l * corr + e;
                #pragma unroll
                for (int c = 0; c < 32; c++) acc[c] = acc[c] * corr + e * Vs[j][c];
                mx = mn;
            }
        }
    }
    if (act) {
        float iv = 1.f / l;
        float* op = AO + ((size_t)(b * 300 + tid) * 17 + kslot) * 256 + h * 32;
        #pragma unroll
        for (int c = 0; c < 32; c++) op[c] = acc[c] * iv;
    }
}

// ---------------- MSDeformAttn sampling ----------------
// grid = NROW blocks; block = 256 = 8 heads x 32 hd
__global__ __launch_bounds__(256) void k_msda(const float* __restrict__ OFF,
                                              const float* __restrict__ AWL,
                                              const float* __restrict__ REF,
                                              const float* __restrict__ VAL,
                                              float* __restrict__ OUT) {
    const int Hs[4] = {92, 46, 23, 12};
    const int starts[4] = {0, 8464, 10580, 11109};
    int rowq = blockIdx.x;
    int b = rowq / 5100;
    int tid = threadIdx.x;
    int h = tid >> 5, hd = tid & 31;
    // softmax over 16 attention weights (redundant per lane — tiny)
    const float* awp = AWL + (size_t)rowq * 128 + h * 16;
    float aw[16];
    float m = -1e30f;
    #pragma unroll
    for (int i = 0; i < 16; i++) { aw[i] = awp[i]; m = fmaxf(m, aw[i]); }
    float s = 0.f;
    #pragma unroll
    for (int i = 0; i < 16; i++) { aw[i] = __expf(aw[i] - m); s += aw[i]; }
    float inv = 1.f / s;
    const float* offp = OFF + (size_t)rowq * 256 + h * 32;
    const float* refp = REF + (size_t)rowq * 8;
    float out = 0.f;
    #pragma unroll
    for (int l = 0; l < 4; l++) {
        int Ww = Hs[l];
        float fw = (float)Ww;
        float rx = refp[l * 2], ry = refp[l * 2 + 1];
        const float* vbase = VAL + ((size_t)b * LVV + starts[l]) * 256 + h * 32 + hd;
        #pragma unroll
        for (int p = 0; p < 4; p++) {
            float ox = offp[(l * 4 + p) * 2], oy = offp[(l * 4 + p) * 2 + 1];
            float x = (rx + ox / fw) * fw - 0.5f;
            float y = (ry + oy / fw) * fw - 0.5f;
            float x0f = floorf(x), y0f = floorf(y);
            float wx = x - x0f, wy = y - y0f;
            int x0 = (int)x0f, y0 = (int)y0f;
            float v00 = 0.f, v01 = 0.f, v10 = 0.f, v11 = 0.f;
            bool xv0 = (x0 >= 0) & (x0 < Ww), xv1 = (x0 + 1 >= 0) & (x0 + 1 < Ww);
            bool yv0 = (y0 >= 0) & (y0 < Ww), yv1 = (y0 + 1 >= 0) & (y0 + 1 < Ww);
            if (yv0 && xv0) v00 = vbase[(size_t)(y0 * Ww + x0) * 256];
            if (yv0 && xv1) v01 = vbase[(size_t)(y0 * Ww + x0 + 1) * 256];
            if (yv1 && xv0) v10 = vbase[(size_t)((y0 + 1) * Ww + x0) * 256];
            if (yv1 && xv1) v11 = vbase[(size_t)((y0 + 1) * Ww + x0 + 1) * 256];
            float bi = (1.f - wx) * (1.f - wy) * v00 + wx * (1.f - wy) * v01
                     + (1.f - wx) * wy * v10 + wx * wy * v11;
            out += aw[l * 4 + p] * inv * bi;
        }
    }
    OUT[(size_t)rowq * 256 + h * 32 + hd] = out;
}

// ---------------- launch ----------------
extern "C" void kernel_launch(void* const* d_in, const int* in_sizes, int n_in,
                              void* d_out, int out_size, void* d_ws, size_t ws_size,
                              hipStream_t stream) {
    const float* tgt     = (const float*)d_in[0];
    const float* pos     = (const float*)d_in[1];
    const float* refpts  = (const float*)d_in[2];
    const float* memory  = (const float*)d_in[3];
    // d_in[4] = memory_spatial_shapes (compile-time constants)
    const float* wa_in_w  = (const float*)d_in[5];
    const float* wa_in_b  = (const float*)d_in[6];
    const float* wa_out_w = (const float*)d_in[7];
    const float* wa_out_b = (const float*)d_in[8];
    const float* ac_in_w  = (const float*)d_in[9];
    const float* ac_in_b  = (const float*)d_in[10];
    const float* ac_out_w = (const float*)d_in[11];
    const float* ac_out_b = (const float*)d_in[12];
    const float* ms_val_w = (const float*)d_in[13];
    const float* ms_val_b = (const float*)d_in[14];
    const float* ms_off_w = (const float*)d_in[15];
    const float* ms_off_b = (const float*)d_in[16];
    const float* ms_aw_w  = (const float*)d_in[17];
    const float* ms_aw_b  = (const float*)d_in[18];
    const float* ms_out_w = (const float*)d_in[19];
    const float* ms_out_b = (const float*)d_in[20];
    const float* gate_w   = (const float*)d_in[21];
    const float* gate_b   = (const float*)d_in[22];
    const float* l1_w     = (const float*)d_in[23];
    const float* l1_b     = (const float*)d_in[24];
    const float* l2_w     = (const float*)d_in[25];
    const float* l2_b     = (const float*)d_in[26];
    const float* gn_g     = (const float*)d_in[27];
    const float* wn_g     = (const float*)d_in[28];
    const float* an_g     = (const float*)d_in[29];
    const float* n2_g     = (const float*)d_in[30];
    const float* gn_b     = (const float*)d_in[31];
    const float* wn_b     = (const float*)d_in[32];
    const float* an_b     = (const float*)d_in[33];
    const float* n2_b     = (const float*)d_in[34];

    float* ws = (float*)d_ws;
    const size_t SROW = (size_t)NROW * 256;   // 5,222,400 floats per 20400x256 tensor
    float* TP  = ws;                          // running activation
    float* Qb  = ws + SROW;                   // pos-added query
    float* T2  = ws + 2 * SROW;               // branch output
    float* BIG = ws + 3 * SROW;               // 20400 x 1024 scratch
    // MSDA phase: OFF/AW in BIG's head, VAL in its tail (starts at col 384)
    float* OFF = BIG;                                     // 20400 x 256
    float* AW  = BIG + SROW;                              // 20400 x 128
    float* VAL = BIG + (size_t)NROW * 384;                // 45012 x 256 (11.5M floats, fits)
    // Gate phase: gi in first half, GATES in second half
    float* GI    = BIG;                                   // 20400 x 512
    float* GATES = BIG + (size_t)NROW * 512;              // 20400 x 512
    float* Xb  = (float*)d_out;               // x buffer; final LN writes here too

    const int n4 = NROW * 64;                  // float4 count of a 20400x256 tensor
    const int gx = (NROW + 63) / 64;           // 319
    const int gxv = (BSZ * LVV + 63) / 64;     // 704

    // 1. TP = tgt + pos
    k_add<<<(n4 + 255) / 256, 256, 0, stream>>>((const float4*)tgt, (const float4*)pos, (float4*)TP, n4);
    // 2. wa QKV
    k_gemm_mfma<0><<<dim3(gx, 12), 256, 0, stream>>>(TP, wa_in_w, wa_in_b, BIG, NROW, 768, 256);
    // 3. within-attn
    k_wattn<<<1200 * 8, 64, 0, stream>>>(BIG, T2);
    // 4. wa out proj
    k_gemm_mfma<0><<<dim3(gx, 4), 256, 0, stream>>>(T2, wa_out_w, wa_out_b, Xb, NROW, 256, 256);
    // 5. TP = LN(TP + Xb; wn)
    k_ln_res<<<(NROW + 3) / 4, 256, 0, stream>>>(TP, Xb, wn_g, wn_b, TP, NROW);
    // 6. ac QKV
    k_gemm_mfma<0><<<dim3(gx, 12), 256, 0, stream>>>(TP, ac_in_w, ac_in_b, BIG, NROW, 768, 256);
    // 7. across-attn
    k_acattn<<<BSZ * 17 * 8, 320, 0, stream>>>(BIG, T2);
    // 8. ac out proj
    k_gemm_mfma<0><<<dim3(gx, 4), 256, 0, stream>>>(T2, ac_out_w, ac_out_b, Xb, NROW, 256, 256);
    // 9. TP = LN(TP + Xb; an)
    k_ln_res<<<(NROW + 3) / 4, 256, 0, stream>>>(TP, Xb, an_g, an_b, TP, NROW);
    // 10. Q = TP + pos
    k_add<<<(n4 + 255) / 256, 256, 0, stream>>>((const float4*)TP, (const float4*)pos, (float4*)Qb, n4);
    // 11. val = memory @ ms_val_w.T + b  (into BIG tail)
    k_gemm_mfma<0><<<dim3(gxv, 4), 256, 0, stream>>>(memory, ms_val_w, ms_val_b, VAL, BSZ * LVV, 256, 256);
    // 12. off
    k_gemm_mfma<0><<<dim3(gx, 4), 256, 0, stream>>>(Qb, ms_off_w, ms_off_b, OFF, NROW, 256, 256);
    // 13. aw logits
    k_gemm_mfma<0><<<dim3(gx, 2), 256, 0, stream>>>(Qb, ms_aw_w, ms_aw_b, AW, NROW, 128, 256);
    // 14. sample -> TP (reused as sampled output)
    k_msda<<<NROW, 256, 0, stream>>>(OFF, AW, refpts, VAL, TP);
    // 15. ms out proj
    k_gemm_mfma<0><<<dim3(gx, 4), 256, 0, stream>>>(TP, ms_out_w, ms_out_b, T2, NROW, 256, 256);
    // 16. gi = [Q | T2]  (into BIG first half)
    k_concat<<<(NROW * 128 + 255) / 256, 256, 0, stream>>>((const float4*)Qb, (const float4*)T2, (float4*)GI, NROW);
    // 17. gates = sigmoid(gi @ gate_w.T + b)  (into BIG second half)
    k_gemm_mfma<2><<<dim3(gx, 8), 256, 0, stream>>>(GI, gate_w, gate_b, GATES, NROW, 512, 512);
    // 18. x = LN(g1*Q + g2*T2; gn) -> Xb
    k_ln_gate<<<(NROW + 3) / 4, 256, 0, stream>>>(GATES, Qb, T2, gn_g, gn_b, Xb, NROW);
    // 19. f1 = relu(x @ l1.T + b)
    k_gemm_mfma<1><<<dim3(gx, 16), 256, 0, stream>>>(Xb, l1_w, l1_b, BIG, NROW, 1024, 256);
    // 20. f = f1 @ l2.T + b
    k_gemm_mfma<0><<<dim3(gx, 4), 256, 0, stream>>>(BIG, l2_w, l2_b, T2, NROW, 256, 1024);
    // 21. out = LN(x + f; n2)
    k_ln_res<<<(NROW + 3) / 4, 256, 0, stream>>>(Xb, T2, n2_g, n2_b, (float*)d_out, NROW);
}

// Round 7
// 1038.637 us; speedup vs baseline: 1.1943x; 1.1943x over previous
//
#include <hip/hip_runtime.h>
#include <math.h>

// ---------------- problem constants ----------------
#define DD   256
#define NHH  8
#define HDIM 32
#define NLV  4
#define NPT  4
#define BSZ  4
#define NQQ  300
#define NKK  17
#define LQQ  (NQQ*NKK)      // 5100
#define NROW (BSZ*LQQ)      // 20400
#define LVV  11253
#define FFD  1024

typedef __attribute__((ext_vector_type(8))) short bf16x8;
typedef __attribute__((ext_vector_type(4))) float f32x4;

__device__ __forceinline__ unsigned short f2bf(float f) {
    unsigned int u = __float_as_uint(f);
    u = u + 0x7FFFu + ((u >> 16) & 1u);   // round-to-nearest-even
    return (unsigned short)(u >> 16);
}

// ---------------- elementwise add (float4) ----------------
__global__ __launch_bounds__(256) void k_add(const float4* __restrict__ a,
                                             const float4* __restrict__ b,
                                             float4* __restrict__ o, int n4) {
    int i = blockIdx.x * 256 + threadIdx.x;
    if (i < n4) {
        float4 x = a[i], y = b[i];
        o[i] = make_float4(x.x + y.x, x.y + y.y, x.z + y.z, x.w + y.w);
    }
}

// ---------------- concat [Q | T2] -> 512-wide ----------------
__global__ __launch_bounds__(256) void k_concat(const float4* __restrict__ a,
                                                const float4* __restrict__ b,
                                                float4* __restrict__ o, int rows) {
    int i = blockIdx.x * 256 + threadIdx.x;  // over rows*128 float4s
    if (i >= rows * 128) return;
    int r = i >> 7, c = i & 127;
    o[i] = (c < 64) ? a[(size_t)r * 64 + c] : b[(size_t)r * 64 + (c - 64)];
}

// ---------------- MFMA GEMM: C = act(A @ B^T + bias) ----------------
template<int ACT>
__global__ __launch_bounds__(256) void k_gemm_mfma(const float* __restrict__ A,
                                                   const float* __restrict__ B,
                                                   const float* __restrict__ bias,
                                                   float* __restrict__ C,
                                                   int M, int N, int K) {
    __shared__ unsigned short As[64][40];
    __shared__ unsigned short Bs[64][40];
    int t = threadIdx.x;
    int lane = t & 63, w = t >> 6;
    int l16 = lane & 15, hi = lane >> 4;
    int row0 = blockIdx.x * 64, col0 = blockIdx.y * 64;
    int srow = t >> 2;            // 0..63  (staging row)
    int scol = (t & 3) * 8;       // 0,8,16,24 (staging col, 8 elems)

    f32x4 acc[4];
    #pragma unroll
    for (int i = 0; i < 4; i++) acc[i] = (f32x4){0.f, 0.f, 0.f, 0.f};

    for (int k0 = 0; k0 < K; k0 += 32) {
        {
            float v[8];
            int gr = row0 + srow;
            if (gr < M) {
                const float4* p = (const float4*)(A + (size_t)gr * K + k0 + scol);
                float4 x = p[0], y = p[1];
                v[0] = x.x; v[1] = x.y; v[2] = x.z; v[3] = x.w;
                v[4] = y.x; v[5] = y.y; v[6] = y.z; v[7] = y.w;
            } else {
                #pragma unroll
                for (int i = 0; i < 8; i++) v[i] = 0.f;
            }
            bf16x8 h;
            #pragma unroll
            for (int i = 0; i < 8; i++) h[i] = (short)f2bf(v[i]);
            *(bf16x8*)&As[srow][scol] = h;
        }
        {
            float v[8];
            int gb = col0 + srow;
            const float4* p = (const float4*)(B + (size_t)gb * K + k0 + scol);
            float4 x = p[0], y = p[1];
            v[0] = x.x; v[1] = x.y; v[2] = x.z; v[3] = x.w;
            v[4] = y.x; v[5] = y.y; v[6] = y.z; v[7] = y.w;
            bf16x8 h;
            #pragma unroll
            for (int i = 0; i < 8; i++) h[i] = (short)f2bf(v[i]);
            *(bf16x8*)&Bs[srow][scol] = h;
        }
        __syncthreads();
        bf16x8 af = *(const bf16x8*)&As[(w << 4) + l16][hi * 8];
        #pragma unroll
        for (int nt = 0; nt < 4; nt++) {
            bf16x8 bf = *(const bf16x8*)&Bs[nt * 16 + l16][hi * 8];
            acc[nt] = __builtin_amdgcn_mfma_f32_16x16x32_bf16(af, bf, acc[nt], 0, 0, 0);
        }
        __syncthreads();
    }
    #pragma unroll
    for (int nt = 0; nt < 4; nt++) {
        int col = col0 + nt * 16 + l16;
        float bv = bias[col];
        #pragma unroll
        for (int r = 0; r < 4; r++) {
            int row = row0 + (w << 4) + (hi << 2) + r;
            if (row < M) {
                float v = acc[nt][r] + bv;
                if (ACT == 1) v = fmaxf(v, 0.f);
                else if (ACT == 2) v = 1.f / (1.f + __expf(-v));
                C[(size_t)row * N + col] = v;
            }
        }
    }
}

// ---------------- LayerNorm(a + b) * g + beta, one wave per row ----------------
__global__ __launch_bounds__(256) void k_ln_res(const float* __restrict__ A,
                                                const float* __restrict__ Bp,
                                                const float* __restrict__ g,
                                                const float* __restrict__ be,
                                                float* __restrict__ O, int M) {
    int row = blockIdx.x * 4 + (threadIdx.x >> 6);
    int lane = threadIdx.x & 63;
    if (row >= M) return;
    float4 a = ((const float4*)A)[(size_t)row * 64 + lane];
    float4 b = ((const float4*)Bp)[(size_t)row * 64 + lane];
    float x0 = a.x + b.x, x1 = a.y + b.y, x2 = a.z + b.z, x3 = a.w + b.w;
    float s = x0 + x1 + x2 + x3;
    float sq = x0 * x0 + x1 * x1 + x2 * x2 + x3 * x3;
    #pragma unroll
    for (int o = 32; o; o >>= 1) { s += __shfl_xor(s, o); sq += __shfl_xor(sq, o); }
    float mean = s * (1.f / 256.f);
    float var = sq * (1.f / 256.f) - mean * mean;
    float rs = rsqrtf(var + 1e-5f);
    float4 gg = ((const float4*)g)[lane];
    float4 bb = ((const float4*)be)[lane];
    float4 o4;
    o4.x = (x0 - mean) * rs * gg.x + bb.x;
    o4.y = (x1 - mean) * rs * gg.y + bb.y;
    o4.z = (x2 - mean) * rs * gg.z + bb.z;
    o4.w = (x3 - mean) * rs * gg.w + bb.w;
    ((float4*)O)[(size_t)row * 64 + lane] = o4;
}

// ---------------- LayerNorm(g1*Q + g2*T2) * g + beta ----------------
__global__ __launch_bounds__(256) void k_ln_gate(const float* __restrict__ G,
                                                 const float* __restrict__ Q,
                                                 const float* __restrict__ T2,
                                                 const float* __restrict__ g,
                                                 const float* __restrict__ be,
                                                 float* __restrict__ O, int M) {
    int row = blockIdx.x * 4 + (threadIdx.x >> 6);
    int lane = threadIdx.x & 63;
    if (row >= M) return;
    float4 g1 = ((const float4*)G)[(size_t)row * 128 + lane];
    float4 g2 = ((const float4*)G)[(size_t)row * 128 + 64 + lane];
    float4 q = ((const float4*)Q)[(size_t)row * 64 + lane];
    float4 t = ((const float4*)T2)[(size_t)row * 64 + lane];
    float x0 = g1.x * q.x + g2.x * t.x;
    float x1 = g1.y * q.y + g2.y * t.y;
    float x2 = g1.z * q.z + g2.z * t.z;
    float x3 = g1.w * q.w + g2.w * t.w;
    float s = x0 + x1 + x2 + x3;
    float sq = x0 * x0 + x1 * x1 + x2 * x2 + x3 * x3;
    #pragma unroll
    for (int o = 32; o; o >>= 1) { s += __shfl_xor(s, o); sq += __shfl_xor(sq, o); }
    float mean = s * (1.f / 256.f);
    float var = sq * (1.f / 256.f) - mean * mean;
    float rs = rsqrtf(var + 1e-5f);
    float4 gg = ((const float4*)g)[lane];
    float4 bb = ((const float4*)be)[lane];
    float4 o4;
    o4.x = (x0 - mean) * rs * gg.x + bb.x;
    o4.y = (x1 - mean) * rs * gg.y + bb.y;
    o4.z = (x2 - mean) * rs * gg.z + bb.z;
    o4.w = (x3 - mean) * rs * gg.w + bb.w;
    ((float4*)O)[(size_t)row * 64 + lane] = o4;
}

// ---------------- within-group attention: seq len 17, one wave per (seq,head) ----------------
__global__ __launch_bounds__(64) void k_wattn(const float* __restrict__ QKV,
                                              float* __restrict__ AO) {
    int unit = blockIdx.x;          // (seq*8 + h), seq in [0,1200)
    int h = unit & 7;
    int sqc = unit >> 3;
    int lane = threadIdx.x;
    __shared__ float q[17][32], kk[17][32], vv[17][32], sc[17][17];
    for (int idx = lane; idx < 17 * 32; idx += 64) {
        int r = idx >> 5, c = idx & 31;
        const float* base = QKV + (size_t)(sqc * 17 + r) * 768 + h * 32 + c;
        q[r][c] = base[0];
        kk[r][c] = base[256];
        vv[r][c] = base[512];
    }
    __syncthreads();
    const float scale = 0.17677669529663687f;  // 1/sqrt(32)
    for (int idx = lane; idx < 289; idx += 64) {
        int i = idx / 17, j = idx % 17;
        float d = 0.f;
        #pragma unroll
        for (int c = 0; c < 32; c++) d += q[i][c] * kk[j][c];
        sc[i][j] = d * scale;
    }
    __syncthreads();
    if (lane < 17) {
        float mm = -1e30f;
        for (int j = 0; j < 17; j++) mm = fmaxf(mm, sc[lane][j]);
        float ss = 0.f;
        for (int j = 0; j < 17; j++) { float e = __expf(sc[lane][j] - mm); sc[lane][j] = e; ss += e; }
        float iv = 1.f / ss;
        for (int j = 0; j < 17; j++) sc[lane][j] *= iv;
    }
    __syncthreads();
    for (int idx = lane; idx < 17 * 32; idx += 64) {
        int i = idx >> 5, c = idx & 31;
        float o = 0.f;
        #pragma unroll
        for (int j = 0; j < 17; j++) o += sc[i][j] * vv[j][c];
        AO[(size_t)(sqc * 17 + i) * 256 + h * 32 + c] = o;
    }
}

// ---------------- across-group attention, MFMA flash version ----------------
// S = Q K^T per (b, kslot, head); 300 queries x 300 keys x hd 32.
// grid = 68 * 8 * 5 blocks; block = 256 threads (4 waves x 16 q-rows = 64 q-rows/block).
// Per 64-key chunk: stage K row-major + V transposed (bf16) in LDS; each wave:
// 4 QK mfma -> masked online softmax (shfl over l16) -> P via per-wave LDS -> 4 PV mfma.
__global__ __launch_bounds__(256) void k_acattn_mfma(const float* __restrict__ QKV,
                                                     float* __restrict__ AO) {
    __shared__ unsigned short Ks[64][40];   // K rows (local key j, hd k)
    __shared__ unsigned short Vt[32][66];   // V transposed: Vt[d][local j]
    __shared__ unsigned short Pl[4][16][72];// per-wave P: [q 0..15][local j 0..63]

    int blk = blockIdx.x;
    int qb = blk % 5;
    int rest = blk / 5;
    int h = rest & 7;
    int bk = rest >> 3;
    int kslot = bk % 17;
    int b = bk / 17;

    int t = threadIdx.x;
    int lane = t & 63, w = t >> 6;
    int l16 = lane & 15, hi = lane >> 4;
    const float scale = 0.17677669529663687f;   // 1/sqrt(32)

    // Q fragment (scale folded in): row q0 + w*16 + l16, k = 8*hi + i
    int q0 = qb * 64;
    int qrow = q0 + (w << 4) + l16;
    int qc = qrow < 300 ? qrow : 299;
    bf16x8 qf;
    {
        const float* qp = QKV + ((size_t)(b * 300 + qc) * 17 + kslot) * 768 + h * 32 + hi * 8;
        float4 x = ((const float4*)qp)[0];
        float4 y = ((const float4*)qp)[1];
        float v[8] = {x.x, x.y, x.z, x.w, y.x, y.y, y.z, y.w};
        #pragma unroll
        for (int i = 0; i < 8; i++) qf[i] = (short)f2bf(v[i] * scale);
    }

    f32x4 acc0 = (f32x4){0.f, 0.f, 0.f, 0.f};
    f32x4 acc1 = (f32x4){0.f, 0.f, 0.f, 0.f};
    float m[4], l[4];
    #pragma unroll
    for (int r = 0; r < 4; r++) { m[r] = -1e30f; l[r] = 0.f; }

    int jl = t >> 2;            // staging row 0..63
    int sc = (t & 3) * 8;       // staging col 0,8,16,24

    for (int c0 = 0; c0 < 300; c0 += 64) {
        __syncthreads();
        // ---- stage K (row-major bf16) and V (transposed bf16) ----
        {
            int krow = c0 + jl; if (krow > 299) krow = 299;
            const float* kp = QKV + ((size_t)(b * 300 + krow) * 17 + kslot) * 768 + 256 + h * 32 + sc;
            float4 x = ((const float4*)kp)[0];
            float4 y = ((const float4*)kp)[1];
            float v[8] = {x.x, x.y, x.z, x.w, y.x, y.y, y.z, y.w};
            bf16x8 hK;
            #pragma unroll
            for (int i = 0; i < 8; i++) hK[i] = (short)f2bf(v[i]);
            *(bf16x8*)&Ks[jl][sc] = hK;
            const float* vp = kp + 256;
            float4 vx = ((const float4*)vp)[0];
            float4 vy = ((const float4*)vp)[1];
            float vv[8] = {vx.x, vx.y, vx.z, vx.w, vy.x, vy.y, vy.z, vy.w};
            #pragma unroll
            for (int i = 0; i < 8; i++) Vt[sc + i][jl] = f2bf(vv[i]);
        }
        __syncthreads();

        // ---- QK^T: 4 tiles of 16 keys ----
        f32x4 S[4];
        #pragma unroll
        for (int jt = 0; jt < 4; jt++) {
            bf16x8 kf = *(const bf16x8*)&Ks[jt * 16 + l16][hi * 8];
            S[jt] = __builtin_amdgcn_mfma_f32_16x16x32_bf16(qf, kf,
                     (f32x4){0.f, 0.f, 0.f, 0.f}, 0, 0, 0);
        }
        // ---- mask invalid keys + chunk max (reduce over l16) ----
        float cm[4] = {-1e30f, -1e30f, -1e30f, -1e30f};
        #pragma unroll
        for (int jt = 0; jt < 4; jt++) {
            bool ok = (c0 + jt * 16 + l16) < 300;
            #pragma unroll
            for (int r = 0; r < 4; r++) {
                float s = ok ? S[jt][r] : -1e30f;
                S[jt][r] = s;
                cm[r] = fmaxf(cm[r], s);
            }
        }
        #pragma unroll
        for (int o = 1; o < 16; o <<= 1)
            #pragma unroll
            for (int r = 0; r < 4; r++) cm[r] = fmaxf(cm[r], __shfl_xor(cm[r], o));
        // ---- online update ----
        float corr[4];
        #pragma unroll
        for (int r = 0; r < 4; r++) {
            float nm = fmaxf(m[r], cm[r]);
            corr[r] = __expf(m[r] - nm);
            m[r] = nm;
        }
        float ps[4] = {0.f, 0.f, 0.f, 0.f};
        #pragma unroll
        for (int jt = 0; jt < 4; jt++)
            #pragma unroll
            for (int r = 0; r < 4; r++) {
                float p = __expf(S[jt][r] - m[r]);
                S[jt][r] = p;
                ps[r] += p;
            }
        #pragma unroll
        for (int o = 1; o < 16; o <<= 1)
            #pragma unroll
            for (int r = 0; r < 4; r++) ps[r] += __shfl_xor(ps[r], o);
        #pragma unroll
        for (int r = 0; r < 4; r++) l[r] = l[r] * corr[r] + ps[r];
        #pragma unroll
        for (int r = 0; r < 4; r++) { acc0[r] *= corr[r]; acc1[r] *= corr[r]; }
        // ---- P -> per-wave LDS (bf16), D-layout row q=4*hi+r, col j=jt*16+l16 ----
        #pragma unroll
        for (int jt = 0; jt < 4; jt++)
            #pragma unroll
            for (int r = 0; r < 4; r++)
                Pl[w][(hi << 2) + r][jt * 16 + l16] = f2bf(S[jt][r]);
        // ---- PV: contraction over 64 keys in two K=32 halves ----
        #pragma unroll
        for (int half = 0; half < 2; half++) {
            bf16x8 pf = *(const bf16x8*)&Pl[w][l16][half * 32 + hi * 8];
            bf16x8 vf0 = *(const bf16x8*)&Vt[l16][half * 32 + hi * 8];
            bf16x8 vf1 = *(const bf16x8*)&Vt[16 + l16][half * 32 + hi * 8];
            acc0 = __builtin_amdgcn_mfma_f32_16x16x32_bf16(pf, vf0, acc0, 0, 0, 0);
            acc1 = __builtin_amdgcn_mfma_f32_16x16x32_bf16(pf, vf1, acc1, 0, 0, 0);
        }
    }
    // ---- epilogue: out[q][d] = acc/l ; D row q = q0+w*16+4*hi+r, col d = l16 / 16+l16 ----
    #pragma unroll
    for (int r = 0; r < 4; r++) {
        int q = q0 + (w << 4) + (hi << 2) + r;
        if (q < 300) {
            float inv = 1.f / l[r];
            float* op = AO + ((size_t)(b * 300 + q) * 17 + kslot) * 256 + h * 32;
            op[l16] = acc0[r] * inv;
            op[16 + l16] = acc1[r] * inv;
        }
    }
}

// ---------------- MSDeformAttn sampling ----------------
__global__ __launch_bounds__(256) void k_msda(const float* __restrict__ OFF,
                                              const float* __restrict__ AWL,
                                              const float* __restrict__ REF,
                                              const float* __restrict__ VAL,
                                              float* __restrict__ OUT) {
    const int Hs[4] = {92, 46, 23, 12};
    const int starts[4] = {0, 8464, 10580, 11109};
    int rowq = blockIdx.x;
    int b = rowq / 5100;
    int tid = threadIdx.x;
    int h = tid >> 5, hd = tid & 31;
    const float* awp = AWL + (size_t)rowq * 128 + h * 16;
    float aw[16];
    float m = -1e30f;
    #pragma unroll
    for (int i = 0; i < 16; i++) { aw[i] = awp[i]; m = fmaxf(m, aw[i]); }
    float s = 0.f;
    #pragma unroll
    for (int i = 0; i < 16; i++) { aw[i] = __expf(aw[i] - m); s += aw[i]; }
    float inv = 1.f / s;
    const float* offp = OFF + (size_t)rowq * 256 + h * 32;
    const float* refp = REF + (size_t)rowq * 8;
    float out = 0.f;
    #pragma unroll
    for (int l = 0; l < 4; l++) {
        int Ww = Hs[l];
        float fw = (float)Ww;
        float rx = refp[l * 2], ry = refp[l * 2 + 1];
        const float* vbase = VAL + ((size_t)b * LVV + starts[l]) * 256 + h * 32 + hd;
        #pragma unroll
        for (int p = 0; p < 4; p++) {
            float ox = offp[(l * 4 + p) * 2], oy = offp[(l * 4 + p) * 2 + 1];
            float x = (rx + ox / fw) * fw - 0.5f;
            float y = (ry + oy / fw) * fw - 0.5f;
            float x0f = floorf(x), y0f = floorf(y);
            float wx = x - x0f, wy = y - y0f;
            int x0 = (int)x0f, y0 = (int)y0f;
            float v00 = 0.f, v01 = 0.f, v10 = 0.f, v11 = 0.f;
            bool xv0 = (x0 >= 0) & (x0 < Ww), xv1 = (x0 + 1 >= 0) & (x0 + 1 < Ww);
            bool yv0 = (y0 >= 0) & (y0 < Ww), yv1 = (y0 + 1 >= 0) & (y0 + 1 < Ww);
            if (yv0 && xv0) v00 = vbase[(size_t)(y0 * Ww + x0) * 256];
            if (yv0 && xv1) v01 = vbase[(size_t)(y0 * Ww + x0 + 1) * 256];
            if (yv1 && xv0) v10 = vbase[(size_t)((y0 + 1) * Ww + x0) * 256];
            if (yv1 && xv1) v11 = vbase[(size_t)((y0 + 1) * Ww + x0 + 1) * 256];
            float bi = (1.f - wx) * (1.f - wy) * v00 + wx * (1.f - wy) * v01
                     + (1.f - wx) * wy * v10 + wx * wy * v11;
            out += aw[l * 4 + p] * inv * bi;
        }
    }
    OUT[(size_t)rowq * 256 + h * 32 + hd] = out;
}

// ---------------- launch ----------------
extern "C" void kernel_launch(void* const* d_in, const int* in_sizes, int n_in,
                              void* d_out, int out_size, void* d_ws, size_t ws_size,
                              hipStream_t stream) {
    const float* tgt     = (const float*)d_in[0];
    const float* pos     = (const float*)d_in[1];
    const float* refpts  = (const float*)d_in[2];
    const float* memory  = (const float*)d_in[3];
    const float* wa_in_w  = (const float*)d_in[5];
    const float* wa_in_b  = (const float*)d_in[6];
    const float* wa_out_w = (const float*)d_in[7];
    const float* wa_out_b = (const float*)d_in[8];
    const float* ac_in_w  = (const float*)d_in[9];
    const float* ac_in_b  = (const float*)d_in[10];
    const float* ac_out_w = (const float*)d_in[11];
    const float* ac_out_b = (const float*)d_in[12];
    const float* ms_val_w = (const float*)d_in[13];
    const float* ms_val_b = (const float*)d_in[14];
    const float* ms_off_w = (const float*)d_in[15];
    const float* ms_off_b = (const float*)d_in[16];
    const float* ms_aw_w  = (const float*)d_in[17];
    const float* ms_aw_b  = (const float*)d_in[18];
    const float* ms_out_w = (const float*)d_in[19];
    const float* ms_out_b = (const float*)d_in[20];
    const float* gate_w   = (const float*)d_in[21];
    const float* gate_b   = (const float*)d_in[22];
    const float* l1_w     = (const float*)d_in[23];
    const float* l1_b     = (const float*)d_in[24];
    const float* l2_w     = (const float*)d_in[25];
    const float* l2_b     = (const float*)d_in[26];
    const float* gn_g     = (const float*)d_in[27];
    const float* wn_g     = (const float*)d_in[28];
    const float* an_g     = (const float*)d_in[29];
    const float* n2_g     = (const float*)d_in[30];
    const float* gn_b     = (const float*)d_in[31];
    const float* wn_b     = (const float*)d_in[32];
    const float* an_b     = (const float*)d_in[33];
    const float* n2_b     = (const float*)d_in[34];

    float* ws = (float*)d_ws;
    const size_t SROW = (size_t)NROW * 256;   // floats per 20400x256 tensor
    float* TP  = ws;
    float* Qb  = ws + SROW;
    float* T2  = ws + 2 * SROW;
    float* BIG = ws + 3 * SROW;               // 20400 x 1024 scratch
    float* OFF = BIG;                                     // 20400 x 256
    float* AW  = BIG + SROW;                              // 20400 x 128
    float* VAL = BIG + (size_t)NROW * 384;                // 45012 x 256
    float* GI    = BIG;                                   // 20400 x 512
    float* GATES = BIG + (size_t)NROW * 512;              // 20400 x 512
    float* Xb  = (float*)d_out;

    const int n4 = NROW * 64;
    const int gx = (NROW + 63) / 64;           // 319
    const int gxv = (BSZ * LVV + 63) / 64;     // 704

    // 1. TP = tgt + pos
    k_add<<<(n4 + 255) / 256, 256, 0, stream>>>((const float4*)tgt, (const float4*)pos, (float4*)TP, n4);
    // 2. wa QKV
    k_gemm_mfma<0><<<dim3(gx, 12), 256, 0, stream>>>(TP, wa_in_w, wa_in_b, BIG, NROW, 768, 256);
    // 3. within-attn
    k_wattn<<<1200 * 8, 64, 0, stream>>>(BIG, T2);
    // 4. wa out proj
    k_gemm_mfma<0><<<dim3(gx, 4), 256, 0, stream>>>(T2, wa_out_w, wa_out_b, Xb, NROW, 256, 256);
    // 5. TP = LN(TP + Xb; wn)
    k_ln_res<<<(NROW + 3) / 4, 256, 0, stream>>>(TP, Xb, wn_g, wn_b, TP, NROW);
    // 6. ac QKV
    k_gemm_mfma<0><<<dim3(gx, 12), 256, 0, stream>>>(TP, ac_in_w, ac_in_b, BIG, NROW, 768, 256);
    // 7. across-attn (MFMA flash)
    k_acattn_mfma<<<68 * 8 * 5, 256, 0, stream>>>(BIG, T2);
    // 8. ac out proj
    k_gemm_mfma<0><<<dim3(gx, 4), 256, 0, stream>>>(T2, ac_out_w, ac_out_b, Xb, NROW, 256, 256);
    // 9. TP = LN(TP + Xb; an)
    k_ln_res<<<(NROW + 3) / 4, 256, 0, stream>>>(TP, Xb, an_g, an_b, TP, NROW);
    // 10. Q = TP + pos
    k_add<<<(n4 + 255) / 256, 256, 0, stream>>>((const float4*)TP, (const float4*)pos, (float4*)Qb, n4);
    // 11. val = memory @ ms_val_w.T + b  (into BIG tail)
    k_gemm_mfma<0><<<dim3(gxv, 4), 256, 0, stream>>>(memory, ms_val_w, ms_val_b, VAL, BSZ * LVV, 256, 256);
    // 12. off
    k_gemm_mfma<0><<<dim3(gx, 4), 256, 0, stream>>>(Qb, ms_off_w, ms_off_b, OFF, NROW, 256, 256);
    // 13. aw logits
    k_gemm_mfma<0><<<dim3(gx, 2), 256, 0, stream>>>(Qb, ms_aw_w, ms_aw_b, AW, NROW, 128, 256);
    // 14. sample -> TP
    k_msda<<<NROW, 256, 0, stream>>>(OFF, AW, refpts, VAL, TP);
    // 15. ms out proj
    k_gemm_mfma<0><<<dim3(gx, 4), 256, 0, stream>>>(TP, ms_out_w, ms_out_b, T2, NROW, 256, 256);
    // 16. gi = [Q | T2]
    k_concat<<<(NROW * 128 + 255) / 256, 256, 0, stream>>>((const float4*)Qb, (const float4*)T2, (float4*)GI, NROW);
    // 17. gates = sigmoid(gi @ gate_w.T + b)
    k_gemm_mfma<2><<<dim3(gx, 8), 256, 0, stream>>>(GI, gate_w, gate_b, GATES, NROW, 512, 512);
    // 18. x = LN(g1*Q + g2*T2; gn) -> Xb
    k_ln_gate<<<(NROW + 3) / 4, 256, 0, stream>>>(GATES, Qb, T2, gn_g, gn_b, Xb, NROW);
    // 19. f1 = relu(x @ l1.T + b)
    k_gemm_mfma<1><<<dim3(gx, 16), 256, 0, stream>>>(Xb, l1_w, l1_b, BIG, NROW, 1024, 256);
    // 20. f = f1 @ l2.T + b
    k_gemm_mfma<0><<<dim3(gx, 4), 256, 0, stream>>>(BIG, l2_w, l2_b, T2, NROW, 256, 1024);
    // 21. out = LN(x + f; n2)
    k_ln_res<<<(NROW + 3) / 4, 256, 0, stream>>>(Xb, T2, n2_g, n2_b, (float*)d_out, NROW);
}

// Round 10
// 864.506 us; speedup vs baseline: 1.4349x; 1.2014x over previous
//
#include <hip/hip_runtime.h>
#include <math.h>

// ---------------- problem constants ----------------
#define DD   256
#define NHH  8
#define HDIM 32
#define NLV  4
#define NPT  4
#define BSZ  4
#define NQQ  300
#define NKK  17
#define LQQ  (NQQ*NKK)      // 5100
#define NROW (BSZ*LQQ)      // 20400
#define LVV  11253
#define FFD  1024

typedef __attribute__((ext_vector_type(8))) short bf16x8;
typedef __attribute__((ext_vector_type(4))) float f32x4;

__device__ __forceinline__ unsigned short f2bf(float f) {
    unsigned int u = __float_as_uint(f);
    u = u + 0x7FFFu + ((u >> 16) & 1u);   // round-to-nearest-even
    return (unsigned short)(u >> 16);
}

// ---------------- elementwise add (float4) ----------------
__global__ __launch_bounds__(256) void k_add(const float4* __restrict__ a,
                                             const float4* __restrict__ b,
                                             float4* __restrict__ o, int n4) {
    int i = blockIdx.x * 256 + threadIdx.x;
    if (i < n4) {
        float4 x = a[i], y = b[i];
        o[i] = make_float4(x.x + y.x, x.y + y.y, x.z + y.z, x.w + y.w);
    }
}

// ---------------- concat [Q | T2] -> 512-wide ----------------
__global__ __launch_bounds__(256) void k_concat(const float4* __restrict__ a,
                                                const float4* __restrict__ b,
                                                float4* __restrict__ o, int rows) {
    int i = blockIdx.x * 256 + threadIdx.x;  // over rows*128 float4s
    if (i >= rows * 128) return;
    int r = i >> 7, c = i & 127;
    o[i] = (c < 64) ? a[(size_t)r * 64 + c] : b[(size_t)r * 64 + (c - 64)];
}

// ---------------- MFMA GEMM: C = act(A @ B^T + bias) ----------------
template<int ACT>
__global__ __launch_bounds__(256) void k_gemm_mfma(const float* __restrict__ A,
                                                   const float* __restrict__ B,
                                                   const float* __restrict__ bias,
                                                   float* __restrict__ C,
                                                   int M, int N, int K) {
    __shared__ unsigned short As[64][40];
    __shared__ unsigned short Bs[64][40];
    int t = threadIdx.x;
    int lane = t & 63, w = t >> 6;
    int l16 = lane & 15, hi = lane >> 4;
    int row0 = blockIdx.x * 64, col0 = blockIdx.y * 64;
    int srow = t >> 2;            // 0..63  (staging row)
    int scol = (t & 3) * 8;       // 0,8,16,24 (staging col, 8 elems)

    f32x4 acc[4];
    #pragma unroll
    for (int i = 0; i < 4; i++) acc[i] = (f32x4){0.f, 0.f, 0.f, 0.f};

    for (int k0 = 0; k0 < K; k0 += 32) {
        {
            float v[8];
            int gr = row0 + srow;
            if (gr < M) {
                const float4* p = (const float4*)(A + (size_t)gr * K + k0 + scol);
                float4 x = p[0], y = p[1];
                v[0] = x.x; v[1] = x.y; v[2] = x.z; v[3] = x.w;
                v[4] = y.x; v[5] = y.y; v[6] = y.z; v[7] = y.w;
            } else {
                #pragma unroll
                for (int i = 0; i < 8; i++) v[i] = 0.f;
            }
            bf16x8 h;
            #pragma unroll
            for (int i = 0; i < 8; i++) h[i] = (short)f2bf(v[i]);
            *(bf16x8*)&As[srow][scol] = h;
        }
        {
            float v[8];
            int gb = col0 + srow;
            const float4* p = (const float4*)(B + (size_t)gb * K + k0 + scol);
            float4 x = p[0], y = p[1];
            v[0] = x.x; v[1] = x.y; v[2] = x.z; v[3] = x.w;
            v[4] = y.x; v[5] = y.y; v[6] = y.z; v[7] = y.w;
            bf16x8 h;
            #pragma unroll
            for (int i = 0; i < 8; i++) h[i] = (short)f2bf(v[i]);
            *(bf16x8*)&Bs[srow][scol] = h;
        }
        __syncthreads();
        bf16x8 af = *(const bf16x8*)&As[(w << 4) + l16][hi * 8];
        #pragma unroll
        for (int nt = 0; nt < 4; nt++) {
            bf16x8 bf = *(const bf16x8*)&Bs[nt * 16 + l16][hi * 8];
            acc[nt] = __builtin_amdgcn_mfma_f32_16x16x32_bf16(af, bf, acc[nt], 0, 0, 0);
        }
        __syncthreads();
    }
    #pragma unroll
    for (int nt = 0; nt < 4; nt++) {
        int col = col0 + nt * 16 + l16;
        float bv = bias[col];
        #pragma unroll
        for (int r = 0; r < 4; r++) {
            int row = row0 + (w << 4) + (hi << 2) + r;
            if (row < M) {
                float v = acc[nt][r] + bv;
                if (ACT == 1) v = fmaxf(v, 0.f);
                else if (ACT == 2) v = 1.f / (1.f + __expf(-v));
                C[(size_t)row * N + col] = v;
            }
        }
    }
}

// ---------------- LayerNorm(a + b) * g + beta, one wave per row ----------------
__global__ __launch_bounds__(256) void k_ln_res(const float* __restrict__ A,
                                                const float* __restrict__ Bp,
                                                const float* __restrict__ g,
                                                const float* __restrict__ be,
                                                float* __restrict__ O, int M) {
    int row = blockIdx.x * 4 + (threadIdx.x >> 6);
    int lane = threadIdx.x & 63;
    if (row >= M) return;
    float4 a = ((const float4*)A)[(size_t)row * 64 + lane];
    float4 b = ((const float4*)Bp)[(size_t)row * 64 + lane];
    float x0 = a.x + b.x, x1 = a.y + b.y, x2 = a.z + b.z, x3 = a.w + b.w;
    float s = x0 + x1 + x2 + x3;
    float sq = x0 * x0 + x1 * x1 + x2 * x2 + x3 * x3;
    #pragma unroll
    for (int o = 32; o; o >>= 1) { s += __shfl_xor(s, o); sq += __shfl_xor(sq, o); }
    float mean = s * (1.f / 256.f);
    float var = sq * (1.f / 256.f) - mean * mean;
    float rs = rsqrtf(var + 1e-5f);
    float4 gg = ((const float4*)g)[lane];
    float4 bb = ((const float4*)be)[lane];
    float4 o4;
    o4.x = (x0 - mean) * rs * gg.x + bb.x;
    o4.y = (x1 - mean) * rs * gg.y + bb.y;
    o4.z = (x2 - mean) * rs * gg.z + bb.z;
    o4.w = (x3 - mean) * rs * gg.w + bb.w;
    ((float4*)O)[(size_t)row * 64 + lane] = o4;
}

// ---------------- LayerNorm(g1*Q + g2*T2) * g + beta ----------------
__global__ __launch_bounds__(256) void k_ln_gate(const float* __restrict__ G,
                                                 const float* __restrict__ Q,
                                                 const float* __restrict__ T2,
                                                 const float* __restrict__ g,
                                                 const float* __restrict__ be,
                                                 float* __restrict__ O, int M) {
    int row = blockIdx.x * 4 + (threadIdx.x >> 6);
    int lane = threadIdx.x & 63;
    if (row >= M) return;
    float4 g1 = ((const float4*)G)[(size_t)row * 128 + lane];
    float4 g2 = ((const float4*)G)[(size_t)row * 128 + 64 + lane];
    float4 q = ((const float4*)Q)[(size_t)row * 64 + lane];
    float4 t = ((const float4*)T2)[(size_t)row * 64 + lane];
    float x0 = g1.x * q.x + g2.x * t.x;
    float x1 = g1.y * q.y + g2.y * t.y;
    float x2 = g1.z * q.z + g2.z * t.z;
    float x3 = g1.w * q.w + g2.w * t.w;
    float s = x0 + x1 + x2 + x3;
    float sq = x0 * x0 + x1 * x1 + x2 * x2 + x3 * x3;
    #pragma unroll
    for (int o = 32; o; o >>= 1) { s += __shfl_xor(s, o); sq += __shfl_xor(sq, o); }
    float mean = s * (1.f / 256.f);
    float var = sq * (1.f / 256.f) - mean * mean;
    float rs = rsqrtf(var + 1e-5f);
    float4 gg = ((const float4*)g)[lane];
    float4 bb = ((const float4*)be)[lane];
    float4 o4;
    o4.x = (x0 - mean) * rs * gg.x + bb.x;
    o4.y = (x1 - mean) * rs * gg.y + bb.y;
    o4.z = (x2 - mean) * rs * gg.z + bb.z;
    o4.w = (x3 - mean) * rs * gg.w + bb.w;
    ((float4*)O)[(size_t)row * 64 + lane] = o4;
}

// ---------------- within-group attention: seq len 17, one wave per (seq,head) ----------------
__global__ __launch_bounds__(64) void k_wattn(const float* __restrict__ QKV,
                                              float* __restrict__ AO) {
    int unit = blockIdx.x;          // (seq*8 + h), seq in [0,1200)
    int h = unit & 7;
    int sqc = unit >> 3;
    int lane = threadIdx.x;
    __shared__ float q[17][32], kk[17][32], vv[17][32], sc[17][17];
    for (int idx = lane; idx < 17 * 32; idx += 64) {
        int r = idx >> 5, c = idx & 31;
        const float* base = QKV + (size_t)(sqc * 17 + r) * 768 + h * 32 + c;
        q[r][c] = base[0];
        kk[r][c] = base[256];
        vv[r][c] = base[512];
    }
    __syncthreads();
    const float scale = 0.17677669529663687f;  // 1/sqrt(32)
    for (int idx = lane; idx < 289; idx += 64) {
        int i = idx / 17, j = idx % 17;
        float d = 0.f;
        #pragma unroll
        for (int c = 0; c < 32; c++) d += q[i][c] * kk[j][c];
        sc[i][j] = d * scale;
    }
    __syncthreads();
    if (lane < 17) {
        float mm = -1e30f;
        for (int j = 0; j < 17; j++) mm = fmaxf(mm, sc[lane][j]);
        float ss = 0.f;
        for (int j = 0; j < 17; j++) { float e = __expf(sc[lane][j] - mm); sc[lane][j] = e; ss += e; }
        float iv = 1.f / ss;
        for (int j = 0; j < 17; j++) sc[lane][j] *= iv;
    }
    __syncthreads();
    for (int idx = lane; idx < 17 * 32; idx += 64) {
        int i = idx >> 5, c = idx & 31;
        float o = 0.f;
        #pragma unroll
        for (int j = 0; j < 17; j++) o += sc[i][j] * vv[j][c];
        AO[(size_t)(sqc * 17 + i) * 256 + h * 32 + c] = o;
    }
}

// ---------------- across-group attention, MFMA flash version ----------------
__global__ __launch_bounds__(256) void k_acattn_mfma(const float* __restrict__ QKV,
                                                     float* __restrict__ AO) {
    __shared__ unsigned short Ks[64][40];   // K rows (local key j, hd k)
    __shared__ unsigned short Vt[32][66];   // V transposed: Vt[d][local j]
    __shared__ unsigned short Pl[4][16][72];// per-wave P: [q 0..15][local j 0..63]

    int blk = blockIdx.x;
    int qb = blk % 5;
    int rest = blk / 5;
    int h = rest & 7;
    int bk = rest >> 3;
    int kslot = bk % 17;
    int b = bk / 17;

    int t = threadIdx.x;
    int lane = t & 63, w = t >> 6;
    int l16 = lane & 15, hi = lane >> 4;
    const float scale = 0.17677669529663687f;   // 1/sqrt(32)

    int q0 = qb * 64;
    int qrow = q0 + (w << 4) + l16;
    int qc = qrow < 300 ? qrow : 299;
    bf16x8 qf;
    {
        const float* qp = QKV + ((size_t)(b * 300 + qc) * 17 + kslot) * 768 + h * 32 + hi * 8;
        float4 x = ((const float4*)qp)[0];
        float4 y = ((const float4*)qp)[1];
        float v[8] = {x.x, x.y, x.z, x.w, y.x, y.y, y.z, y.w};
        #pragma unroll
        for (int i = 0; i < 8; i++) qf[i] = (short)f2bf(v[i] * scale);
    }

    f32x4 acc0 = (f32x4){0.f, 0.f, 0.f, 0.f};
    f32x4 acc1 = (f32x4){0.f, 0.f, 0.f, 0.f};
    float m[4], l[4];
    #pragma unroll
    for (int r = 0; r < 4; r++) { m[r] = -1e30f; l[r] = 0.f; }

    int jl = t >> 2;            // staging row 0..63
    int sc = (t & 3) * 8;       // staging col 0,8,16,24

    for (int c0 = 0; c0 < 300; c0 += 64) {
        __syncthreads();
        {
            int krow = c0 + jl; if (krow > 299) krow = 299;
            const float* kp = QKV + ((size_t)(b * 300 + krow) * 17 + kslot) * 768 + 256 + h * 32 + sc;
            float4 x = ((const float4*)kp)[0];
            float4 y = ((const float4*)kp)[1];
            float v[8] = {x.x, x.y, x.z, x.w, y.x, y.y, y.z, y.w};
            bf16x8 hK;
            #pragma unroll
            for (int i = 0; i < 8; i++) hK[i] = (short)f2bf(v[i]);
            *(bf16x8*)&Ks[jl][sc] = hK;
            const float* vp = kp + 256;
            float4 vx = ((const float4*)vp)[0];
            float4 vy = ((const float4*)vp)[1];
            float vv[8] = {vx.x, vx.y, vx.z, vx.w, vy.x, vy.y, vy.z, vy.w};
            #pragma unroll
            for (int i = 0; i < 8; i++) Vt[sc + i][jl] = f2bf(vv[i]);
        }
        __syncthreads();

        f32x4 S[4];
        #pragma unroll
        for (int jt = 0; jt < 4; jt++) {
            bf16x8 kf = *(const bf16x8*)&Ks[jt * 16 + l16][hi * 8];
            S[jt] = __builtin_amdgcn_mfma_f32_16x16x32_bf16(qf, kf,
                     (f32x4){0.f, 0.f, 0.f, 0.f}, 0, 0, 0);
        }
        float cm[4] = {-1e30f, -1e30f, -1e30f, -1e30f};
        #pragma unroll
        for (int jt = 0; jt < 4; jt++) {
            bool ok = (c0 + jt * 16 + l16) < 300;
            #pragma unroll
            for (int r = 0; r < 4; r++) {
                float s = ok ? S[jt][r] : -1e30f;
                S[jt][r] = s;
                cm[r] = fmaxf(cm[r], s);
            }
        }
        #pragma unroll
        for (int o = 1; o < 16; o <<= 1)
            #pragma unroll
            for (int r = 0; r < 4; r++) cm[r] = fmaxf(cm[r], __shfl_xor(cm[r], o));
        float corr[4];
        #pragma unroll
        for (int r = 0; r < 4; r++) {
            float nm = fmaxf(m[r], cm[r]);
            corr[r] = __expf(m[r] - nm);
            m[r] = nm;
        }
        float ps[4] = {0.f, 0.f, 0.f, 0.f};
        #pragma unroll
        for (int jt = 0; jt < 4; jt++)
            #pragma unroll
            for (int r = 0; r < 4; r++) {
                float p = __expf(S[jt][r] - m[r]);
                S[jt][r] = p;
                ps[r] += p;
            }
        #pragma unroll
        for (int o = 1; o < 16; o <<= 1)
            #pragma unroll
            for (int r = 0; r < 4; r++) ps[r] += __shfl_xor(ps[r], o);
        #pragma unroll
        for (int r = 0; r < 4; r++) l[r] = l[r] * corr[r] + ps[r];
        #pragma unroll
        for (int r = 0; r < 4; r++) { acc0[r] *= corr[r]; acc1[r] *= corr[r]; }
        #pragma unroll
        for (int jt = 0; jt < 4; jt++)
            #pragma unroll
            for (int r = 0; r < 4; r++)
                Pl[w][(hi << 2) + r][jt * 16 + l16] = f2bf(S[jt][r]);
        #pragma unroll
        for (int half = 0; half < 2; half++) {
            bf16x8 pf = *(const bf16x8*)&Pl[w][l16][half * 32 + hi * 8];
            bf16x8 vf0 = *(const bf16x8*)&Vt[l16][half * 32 + hi * 8];
            bf16x8 vf1 = *(const bf16x8*)&Vt[16 + l16][half * 32 + hi * 8];
            acc0 = __builtin_amdgcn_mfma_f32_16x16x32_bf16(pf, vf0, acc0, 0, 0, 0);
            acc1 = __builtin_amdgcn_mfma_f32_16x16x32_bf16(pf, vf1, acc1, 0, 0, 0);
        }
    }
    #pragma unroll
    for (int r = 0; r < 4; r++) {
        int q = q0 + (w << 4) + (hi << 2) + r;
        if (q < 300) {
            float inv = 1.f / l[r];
            float* op = AO + ((size_t)(b * 300 + q) * 17 + kslot) * 256 + h * 32;
            op[l16] = acc0[r] * inv;
            op[16 + l16] = acc1[r] * inv;
        }
    }
}

// ---------------- MSDeformAttn sampling, two-phase ----------------
// Phase 1 (128 threads = 8 heads x 16 samples): softmax(aw) via 16-lane shfl,
// coords, validity-masked bilinear weights (aw folded), clamped VAL row indices -> LDS.
// Phase 2 (256 threads = 8 heads x 32 hd): 16 samples x 4 gather-FMAs, LDS broadcast.
__global__ __launch_bounds__(256) void k_msda(const float* __restrict__ OFF,
                                              const float* __restrict__ AWL,
                                              const float* __restrict__ REF,
                                              const float* __restrict__ VAL,
                                              float* __restrict__ OUT) {
    __shared__ int   sIdx[128][4];
    __shared__ float sWgt[128][4];
    const int Hs[4] = {92, 46, 23, 12};
    const int starts[4] = {0, 8464, 10580, 11109};
    int rowq = blockIdx.x;
    int b = rowq / 5100;
    int tid = threadIdx.x;

    if (tid < 128) {
        int h = tid >> 4, p = tid & 15;
        float logit = AWL[(size_t)rowq * 128 + h * 16 + p];
        float mx = logit;
        #pragma unroll
        for (int o = 1; o < 16; o <<= 1) mx = fmaxf(mx, __shfl_xor(mx, o));
        float e = __expf(logit - mx);
        float ssum = e;
        #pragma unroll
        for (int o = 1; o < 16; o <<= 1) ssum += __shfl_xor(ssum, o);
        float aw = e / ssum;

        int l = p >> 2;
        int Ww = Hs[l];
        float fw = (float)Ww;
        float rx = REF[(size_t)rowq * 8 + l * 2];
        float ry = REF[(size_t)rowq * 8 + l * 2 + 1];
        float ox = OFF[(size_t)rowq * 256 + h * 32 + p * 2];
        float oy = OFF[(size_t)rowq * 256 + h * 32 + p * 2 + 1];
        float x = (rx + ox / fw) * fw - 0.5f;
        float y = (ry + oy / fw) * fw - 0.5f;
        float x0f = floorf(x), y0f = floorf(y);
        float wx = x - x0f, wy = y - y0f;
        int x0 = (int)x0f, y0 = (int)y0f;
        bool xv0 = (x0 >= 0) & (x0 < Ww), xv1 = (x0 + 1 >= 0) & (x0 + 1 < Ww);
        bool yv0 = (y0 >= 0) & (y0 < Ww), yv1 = (y0 + 1 >= 0) & (y0 + 1 < Ww);
        int x0c = min(max(x0, 0), Ww - 1), x1c = min(max(x0 + 1, 0), Ww - 1);
        int y0c = min(max(y0, 0), Ww - 1), y1c = min(max(y0 + 1, 0), Ww - 1);
        int base = b * LVV + starts[l];
        sIdx[tid][0] = base + y0c * Ww + x0c;
        sIdx[tid][1] = base + y0c * Ww + x1c;
        sIdx[tid][2] = base + y1c * Ww + x0c;
        sIdx[tid][3] = base + y1c * Ww + x1c;
        sWgt[tid][0] = (yv0 && xv0) ? (1.f - wx) * (1.f - wy) * aw : 0.f;
        sWgt[tid][1] = (yv0 && xv1) ? wx * (1.f - wy) * aw : 0.f;
        sWgt[tid][2] = (yv1 && xv0) ? (1.f - wx) * wy * aw : 0.f;
        sWgt[tid][3] = (yv1 && xv1) ? wx * wy * aw : 0.f;
    }
    __syncthreads();

    int h = tid >> 5, hd = tid & 31;
    int off = h * 32 + hd;
    float out = 0.f;
    #pragma unroll
    for (int p = 0; p < 16; p++) {
        int mI = h * 16 + p;
        int i0 = sIdx[mI][0], i1 = sIdx[mI][1], i2 = sIdx[mI][2], i3 = sIdx[mI][3];
        float w0 = sWgt[mI][0], w1 = sWgt[mI][1], w2 = sWgt[mI][2], w3 = sWgt[mI][3];
        out += w0 * VAL[(size_t)i0 * 256 + off]
             + w1 * VAL[(size_t)i1 * 256 + off]
             + w2 * VAL[(size_t)i2 * 256 + off]
             + w3 * VAL[(size_t)i3 * 256 + off];
    }
    OUT[(size_t)rowq * 256 + off] = out;
}

// ---------------- launch ----------------
extern "C" void kernel_launch(void* const* d_in, const int* in_sizes, int n_in,
                              void* d_out, int out_size, void* d_ws, size_t ws_size,
                              hipStream_t stream) {
    const float* tgt     = (const float*)d_in[0];
    const float* pos     = (const float*)d_in[1];
    const float* refpts  = (const float*)d_in[2];
    const float* memory  = (const float*)d_in[3];
    const float* wa_in_w  = (const float*)d_in[5];
    const float* wa_in_b  = (const float*)d_in[6];
    const float* wa_out_w = (const float*)d_in[7];
    const float* wa_out_b = (const float*)d_in[8];
    const float* ac_in_w  = (const float*)d_in[9];
    const float* ac_in_b  = (const float*)d_in[10];
    const float* ac_out_w = (const float*)d_in[11];
    const float* ac_out_b = (const float*)d_in[12];
    const float* ms_val_w = (const float*)d_in[13];
    const float* ms_val_b = (const float*)d_in[14];
    const float* ms_off_w = (const float*)d_in[15];
    const float* ms_off_b = (const float*)d_in[16];
    const float* ms_aw_w  = (const float*)d_in[17];
    const float* ms_aw_b  = (const float*)d_in[18];
    const float* ms_out_w = (const float*)d_in[19];
    const float* ms_out_b = (const float*)d_in[20];
    const float* gate_w   = (const float*)d_in[21];
    const float* gate_b   = (const float*)d_in[22];
    const float* l1_w     = (const float*)d_in[23];
    const float* l1_b     = (const float*)d_in[24];
    const float* l2_w     = (const float*)d_in[25];
    const float* l2_b     = (const float*)d_in[26];
    const float* gn_g     = (const float*)d_in[27];
    const float* wn_g     = (const float*)d_in[28];
    const float* an_g     = (const float*)d_in[29];
    const float* n2_g     = (const float*)d_in[30];
    const float* gn_b     = (const float*)d_in[31];
    const float* wn_b     = (const float*)d_in[32];
    const float* an_b     = (const float*)d_in[33];
    const float* n2_b     = (const float*)d_in[34];

    float* ws = (float*)d_ws;
    const size_t SROW = (size_t)NROW * 256;   // floats per 20400x256 tensor
    float* TP  = ws;
    float* Qb  = ws + SROW;
    float* T2  = ws + 2 * SROW;
    float* BIG = ws + 3 * SROW;               // 20400 x 1024 scratch
    float* OFF = BIG;                                     // 20400 x 256
    float* AW  = BIG + SROW;                              // 20400 x 128
    float* VAL = BIG + (size_t)NROW * 384;                // 45012 x 256
    float* GI    = BIG;                                   // 20400 x 512
    float* GATES = BIG + (size_t)NROW * 512;              // 20400 x 512
    float* Xb  = (float*)d_out;

    const int n4 = NROW * 64;
    const int gx = (NROW + 63) / 64;           // 319
    const int gxv = (BSZ * LVV + 63) / 64;     // 704

    // 1. TP = tgt + pos
    k_add<<<(n4 + 255) / 256, 256, 0, stream>>>((const float4*)tgt, (const float4*)pos, (float4*)TP, n4);
    // 2. wa QKV
    k_gemm_mfma<0><<<dim3(gx, 12), 256, 0, stream>>>(TP, wa_in_w, wa_in_b, BIG, NROW, 768, 256);
    // 3. within-attn
    k_wattn<<<1200 * 8, 64, 0, stream>>>(BIG, T2);
    // 4. wa out proj
    k_gemm_mfma<0><<<dim3(gx, 4), 256, 0, stream>>>(T2, wa_out_w, wa_out_b, Xb, NROW, 256, 256);
    // 5. TP = LN(TP + Xb; wn)
    k_ln_res<<<(NROW + 3) / 4, 256, 0, stream>>>(TP, Xb, wn_g, wn_b, TP, NROW);
    // 6. ac QKV
    k_gemm_mfma<0><<<dim3(gx, 12), 256, 0, stream>>>(TP, ac_in_w, ac_in_b, BIG, NROW, 768, 256);
    // 7. across-attn (MFMA flash)
    k_acattn_mfma<<<68 * 8 * 5, 256, 0, stream>>>(BIG, T2);
    // 8. ac out proj
    k_gemm_mfma<0><<<dim3(gx, 4), 256, 0, stream>>>(T2, ac_out_w, ac_out_b, Xb, NROW, 256, 256);
    // 9. TP = LN(TP + Xb; an)
    k_ln_res<<<(NROW + 3) / 4, 256, 0, stream>>>(TP, Xb, an_g, an_b, TP, NROW);
    // 10. Q = TP + pos
    k_add<<<(n4 + 255) / 256, 256, 0, stream>>>((const float4*)TP, (const float4*)pos, (float4*)Qb, n4);
    // 11. val = memory @ ms_val_w.T + b  (into BIG tail)
    k_gemm_mfma<0><<<dim3(gxv, 4), 256, 0, stream>>>(memory, ms_val_w, ms_val_b, VAL, BSZ * LVV, 256, 256);
    // 12. off
    k_gemm_mfma<0><<<dim3(gx, 4), 256, 0, stream>>>(Qb, ms_off_w, ms_off_b, OFF, NROW, 256, 256);
    // 13. aw logits
    k_gemm_mfma<0><<<dim3(gx, 2), 256, 0, stream>>>(Qb, ms_aw_w, ms_aw_b, AW, NROW, 128, 256);
    // 14. sample -> TP
    k_msda<<<NROW, 256, 0, stream>>>(OFF, AW, refpts, VAL, TP);
    // 15. ms out proj
    k_gemm_mfma<0><<<dim3(gx, 4), 256, 0, stream>>>(TP, ms_out_w, ms_out_b, T2, NROW, 256, 256);
    // 16. gi = [Q | T2]
    k_concat<<<(NROW * 128 + 255) / 256, 256, 0, stream>>>((const float4*)Qb, (const float4*)T2, (float4*)GI, NROW);
    // 17. gates = sigmoid(gi @ gate_w.T + b)
    k_gemm_mfma<2><<<dim3(gx, 8), 256, 0, stream>>>(GI, gate_w, gate_b, GATES, NROW, 512, 512);
    // 18. x = LN(g1*Q + g2*T2; gn) -> Xb
    k_ln_gate<<<(NROW + 3) / 4, 256, 0, stream>>>(GATES, Qb, T2, gn_g, gn_b, Xb, NROW);
    // 19. f1 = relu(x @ l1.T + b)
    k_gemm_mfma<1><<<dim3(gx, 16), 256, 0, stream>>>(Xb, l1_w, l1_b, BIG, NROW, 1024, 256);
    // 20. f = f1 @ l2.T + b
    k_gemm_mfma<0><<<dim3(gx, 4), 256, 0, stream>>>(BIG, l2_w, l2_b, T2, NROW, 256, 1024);
    // 21. out = LN(x + f; n2)
    k_ln_res<<<(NROW + 3) / 4, 256, 0, stream>>>(Xb, T2, n2_g, n2_b, (float*)d_out, NROW);
}

// Round 12
// 838.685 us; speedup vs baseline: 1.4791x; 1.0308x over previous
//
#include <hip/hip_runtime.h>
#include <math.h>

// ---------------- problem constants ----------------
#define DD   256
#define NHH  8
#define HDIM 32
#define NLV  4
#define NPT  4
#define BSZ  4
#define NQQ  300
#define NKK  17
#define LQQ  (NQQ*NKK)      // 5100
#define NROW (BSZ*LQQ)      // 20400
#define LVV  11253
#define FFD  1024

typedef __attribute__((ext_vector_type(8))) short bf16x8;
typedef __attribute__((ext_vector_type(4))) float f32x4;

__device__ __forceinline__ unsigned short f2bf(float f) {
    unsigned int u = __float_as_uint(f);
    u = u + 0x7FFFu + ((u >> 16) & 1u);   // round-to-nearest-even
    return (unsigned short)(u >> 16);
}

// ---------------- elementwise add (float4) ----------------
__global__ __launch_bounds__(256) void k_add(const float4* __restrict__ a,
                                             const float4* __restrict__ b,
                                             float4* __restrict__ o, int n4) {
    int i = blockIdx.x * 256 + threadIdx.x;
    if (i < n4) {
        float4 x = a[i], y = b[i];
        o[i] = make_float4(x.x + y.x, x.y + y.y, x.z + y.z, x.w + y.w);
    }
}

// ---------------- concat [Q | T2] -> 512-wide ----------------
__global__ __launch_bounds__(256) void k_concat(const float4* __restrict__ a,
                                                const float4* __restrict__ b,
                                                float4* __restrict__ o, int rows) {
    int i = blockIdx.x * 256 + threadIdx.x;  // over rows*128 float4s
    if (i >= rows * 128) return;
    int r = i >> 7, c = i & 127;
    o[i] = (c < 64) ? a[(size_t)r * 64 + c] : b[(size_t)r * 64 + (c - 64)];
}

// ---------------- MFMA GEMM 128x128 tile: C = act(A @ B^T + bias) ----------------
// A: M x K fp32 row-major; B: N x K fp32 row-major (torch weight); C: M x N fp32.
// 256 threads = 4 waves; wave w owns the 64x64 quadrant (wr=w>>1, wc=w&1),
// computing a 4x4 grid of 16x16 fragments. BK=32. Requires N%128==0, K%32==0.
// ACT: 0 none, 1 relu, 2 sigmoid
template<int ACT>
__global__ __launch_bounds__(256) void k_gemm_mfma(const float* __restrict__ A,
                                                   const float* __restrict__ B,
                                                   const float* __restrict__ bias,
                                                   float* __restrict__ C,
                                                   int M, int N, int K) {
    // rows padded to 40 ushorts (80 B): 16B-aligned b128 reads, <=2-way bank alias (free)
    __shared__ unsigned short As[128][40];
    __shared__ unsigned short Bs[128][40];
    int t = threadIdx.x;
    int lane = t & 63, w = t >> 6;
    int l16 = lane & 15, hi = lane >> 4;
    int wr = (w >> 1) << 6;       // wave row offset in tile (0 or 64)
    int wc = (w & 1) << 6;        // wave col offset in tile (0 or 64)
    int row0 = blockIdx.x * 128, col0 = blockIdx.y * 128;
    int srow = t >> 2;            // 0..63  (staging row, +64 on second half)
    int scol = (t & 3) * 8;       // 0,8,16,24 (staging col, 8 elems)

    f32x4 acc[4][4];
    #pragma unroll
    for (int m = 0; m < 4; m++)
        #pragma unroll
        for (int n = 0; n < 4; n++) acc[m][n] = (f32x4){0.f, 0.f, 0.f, 0.f};

    for (int k0 = 0; k0 < K; k0 += 32) {
        #pragma unroll
        for (int half = 0; half < 2; half++) {
            int r = srow + half * 64;
            // ---- stage A row (fp32 -> bf16), zero-pad beyond M ----
            {
                float v[8];
                int gr = row0 + r;
                if (gr < M) {
                    const float4* p = (const float4*)(A + (size_t)gr * K + k0 + scol);
                    float4 x = p[0], y = p[1];
                    v[0] = x.x; v[1] = x.y; v[2] = x.z; v[3] = x.w;
                    v[4] = y.x; v[5] = y.y; v[6] = y.z; v[7] = y.w;
                } else {
                    #pragma unroll
                    for (int i = 0; i < 8; i++) v[i] = 0.f;
                }
                bf16x8 hh;
                #pragma unroll
                for (int i = 0; i < 8; i++) hh[i] = (short)f2bf(v[i]);
                *(bf16x8*)&As[r][scol] = hh;
            }
            // ---- stage B row (always valid: N % 128 == 0) ----
            {
                int gb = col0 + r;
                const float4* p = (const float4*)(B + (size_t)gb * K + k0 + scol);
                float4 x = p[0], y = p[1];
                float v[8] = {x.x, x.y, x.z, x.w, y.x, y.y, y.z, y.w};
                bf16x8 hh;
                #pragma unroll
                for (int i = 0; i < 8; i++) hh[i] = (short)f2bf(v[i]);
                *(bf16x8*)&Bs[r][scol] = hh;
            }
        }
        __syncthreads();
        // ---- fragments + 16 MFMA ----
        bf16x8 af[4], bfr[4];
        #pragma unroll
        for (int m = 0; m < 4; m++) af[m] = *(const bf16x8*)&As[wr + m * 16 + l16][hi * 8];
        #pragma unroll
        for (int n = 0; n < 4; n++) bfr[n] = *(const bf16x8*)&Bs[wc + n * 16 + l16][hi * 8];
        #pragma unroll
        for (int m = 0; m < 4; m++)
            #pragma unroll
            for (int n = 0; n < 4; n++)
                acc[m][n] = __builtin_amdgcn_mfma_f32_16x16x32_bf16(af[m], bfr[n], acc[m][n], 0, 0, 0);
        __syncthreads();
    }
    // ---- epilogue: D[i][j]: j = lane%16, i = 4*(lane/16)+reg ----
    #pragma unroll
    for (int n = 0; n < 4; n++) {
        int col = col0 + wc + n * 16 + l16;
        float bv = bias[col];
        #pragma unroll
        for (int m = 0; m < 4; m++) {
            #pragma unroll
            for (int r = 0; r < 4; r++) {
                int row = row0 + wr + m * 16 + (hi << 2) + r;
                if (row < M) {
                    float v = acc[m][n][r] + bv;
                    if (ACT == 1) v = fmaxf(v, 0.f);
                    else if (ACT == 2) v = 1.f / (1.f + __expf(-v));
                    C[(size_t)row * N + col] = v;
                }
            }
        }
    }
}

// ---------------- LayerNorm(a + b) * g + beta, one wave per row ----------------
__global__ __launch_bounds__(256) void k_ln_res(const float* __restrict__ A,
                                                const float* __restrict__ Bp,
                                                const float* __restrict__ g,
                                                const float* __restrict__ be,
                                                float* __restrict__ O, int M) {
    int row = blockIdx.x * 4 + (threadIdx.x >> 6);
    int lane = threadIdx.x & 63;
    if (row >= M) return;
    float4 a = ((const float4*)A)[(size_t)row * 64 + lane];
    float4 b = ((const float4*)Bp)[(size_t)row * 64 + lane];
    float x0 = a.x + b.x, x1 = a.y + b.y, x2 = a.z + b.z, x3 = a.w + b.w;
    float s = x0 + x1 + x2 + x3;
    float sq = x0 * x0 + x1 * x1 + x2 * x2 + x3 * x3;
    #pragma unroll
    for (int o = 32; o; o >>= 1) { s += __shfl_xor(s, o); sq += __shfl_xor(sq, o); }
    float mean = s * (1.f / 256.f);
    float var = sq * (1.f / 256.f) - mean * mean;
    float rs = rsqrtf(var + 1e-5f);
    float4 gg = ((const float4*)g)[lane];
    float4 bb = ((const float4*)be)[lane];
    float4 o4;
    o4.x = (x0 - mean) * rs * gg.x + bb.x;
    o4.y = (x1 - mean) * rs * gg.y + bb.y;
    o4.z = (x2 - mean) * rs * gg.z + bb.z;
    o4.w = (x3 - mean) * rs * gg.w + bb.w;
    ((float4*)O)[(size_t)row * 64 + lane] = o4;
}

// ---------------- LayerNorm(g1*Q + g2*T2) * g + beta ----------------
__global__ __launch_bounds__(256) void k_ln_gate(const float* __restrict__ G,
                                                 const float* __restrict__ Q,
                                                 const float* __restrict__ T2,
                                                 const float* __restrict__ g,
                                                 const float* __restrict__ be,
                                                 float* __restrict__ O, int M) {
    int row = blockIdx.x * 4 + (threadIdx.x >> 6);
    int lane = threadIdx.x & 63;
    if (row >= M) return;
    float4 g1 = ((const float4*)G)[(size_t)row * 128 + lane];
    float4 g2 = ((const float4*)G)[(size_t)row * 128 + 64 + lane];
    float4 q = ((const float4*)Q)[(size_t)row * 64 + lane];
    float4 t = ((const float4*)T2)[(size_t)row * 64 + lane];
    float x0 = g1.x * q.x + g2.x * t.x;
    float x1 = g1.y * q.y + g2.y * t.y;
    float x2 = g1.z * q.z + g2.z * t.z;
    float x3 = g1.w * q.w + g2.w * t.w;
    float s = x0 + x1 + x2 + x3;
    float sq = x0 * x0 + x1 * x1 + x2 * x2 + x3 * x3;
    #pragma unroll
    for (int o = 32; o; o >>= 1) { s += __shfl_xor(s, o); sq += __shfl_xor(sq, o); }
    float mean = s * (1.f / 256.f);
    float var = sq * (1.f / 256.f) - mean * mean;
    float rs = rsqrtf(var + 1e-5f);
    float4 gg = ((const float4*)g)[lane];
    float4 bb = ((const float4*)be)[lane];
    float4 o4;
    o4.x = (x0 - mean) * rs * gg.x + bb.x;
    o4.y = (x1 - mean) * rs * gg.y + bb.y;
    o4.z = (x2 - mean) * rs * gg.z + bb.z;
    o4.w = (x3 - mean) * rs * gg.w + bb.w;
    ((float4*)O)[(size_t)row * 64 + lane] = o4;
}

// ---------------- within-group attention: seq len 17, one wave per (seq,head) ----------------
__global__ __launch_bounds__(64) void k_wattn(const float* __restrict__ QKV,
                                              float* __restrict__ AO) {
    int unit = blockIdx.x;          // (seq*8 + h), seq in [0,1200)
    int h = unit & 7;
    int sqc = unit >> 3;
    int lane = threadIdx.x;
    __shared__ float q[17][32], kk[17][32], vv[17][32], sc[17][17];
    for (int idx = lane; idx < 17 * 32; idx += 64) {
        int r = idx >> 5, c = idx & 31;
        const float* base = QKV + (size_t)(sqc * 17 + r) * 768 + h * 32 + c;
        q[r][c] = base[0];
        kk[r][c] = base[256];
        vv[r][c] = base[512];
    }
    __syncthreads();
    const float scale = 0.17677669529663687f;  // 1/sqrt(32)
    for (int idx = lane; idx < 289; idx += 64) {
        int i = idx / 17, j = idx % 17;
        float d = 0.f;
        #pragma unroll
        for (int c = 0; c < 32; c++) d += q[i][c] * kk[j][c];
        sc[i][j] = d * scale;
    }
    __syncthreads();
    if (lane < 17) {
        float mm = -1e30f;
        for (int j = 0; j < 17; j++) mm = fmaxf(mm, sc[lane][j]);
        float ss = 0.f;
        for (int j = 0; j < 17; j++) { float e = __expf(sc[lane][j] - mm); sc[lane][j] = e; ss += e; }
        float iv = 1.f / ss;
        for (int j = 0; j < 17; j++) sc[lane][j] *= iv;
    }
    __syncthreads();
    for (int idx = lane; idx < 17 * 32; idx += 64) {
        int i = idx >> 5, c = idx & 31;
        float o = 0.f;
        #pragma unroll
        for (int j = 0; j < 17; j++) o += sc[i][j] * vv[j][c];
        AO[(size_t)(sqc * 17 + i) * 256 + h * 32 + c] = o;
    }
}

// ---------------- across-group attention, MFMA flash version ----------------
__global__ __launch_bounds__(256) void k_acattn_mfma(const float* __restrict__ QKV,
                                                     float* __restrict__ AO) {
    __shared__ unsigned short Ks[64][40];   // K rows (local key j, hd k)
    __shared__ unsigned short Vt[32][66];   // V transposed: Vt[d][local j]
    __shared__ unsigned short Pl[4][16][72];// per-wave P: [q 0..15][local j 0..63]

    int blk = blockIdx.x;
    int qb = blk % 5;
    int rest = blk / 5;
    int h = rest & 7;
    int bk = rest >> 3;
    int kslot = bk % 17;
    int b = bk / 17;

    int t = threadIdx.x;
    int lane = t & 63, w = t >> 6;
    int l16 = lane & 15, hi = lane >> 4;
    const float scale = 0.17677669529663687f;   // 1/sqrt(32)

    int q0 = qb * 64;
    int qrow = q0 + (w << 4) + l16;
    int qc = qrow < 300 ? qrow : 299;
    bf16x8 qf;
    {
        const float* qp = QKV + ((size_t)(b * 300 + qc) * 17 + kslot) * 768 + h * 32 + hi * 8;
        float4 x = ((const float4*)qp)[0];
        float4 y = ((const float4*)qp)[1];
        float v[8] = {x.x, x.y, x.z, x.w, y.x, y.y, y.z, y.w};
        #pragma unroll
        for (int i = 0; i < 8; i++) qf[i] = (short)f2bf(v[i] * scale);
    }

    f32x4 acc0 = (f32x4){0.f, 0.f, 0.f, 0.f};
    f32x4 acc1 = (f32x4){0.f, 0.f, 0.f, 0.f};
    float m[4], l[4];
    #pragma unroll
    for (int r = 0; r < 4; r++) { m[r] = -1e30f; l[r] = 0.f; }

    int jl = t >> 2;            // staging row 0..63
    int sc = (t & 3) * 8;       // staging col 0,8,16,24

    for (int c0 = 0; c0 < 300; c0 += 64) {
        __syncthreads();
        {
            int krow = c0 + jl; if (krow > 299) krow = 299;
            const float* kp = QKV + ((size_t)(b * 300 + krow) * 17 + kslot) * 768 + 256 + h * 32 + sc;
            float4 x = ((const float4*)kp)[0];
            float4 y = ((const float4*)kp)[1];
            float v[8] = {x.x, x.y, x.z, x.w, y.x, y.y, y.z, y.w};
            bf16x8 hK;
            #pragma unroll
            for (int i = 0; i < 8; i++) hK[i] = (short)f2bf(v[i]);
            *(bf16x8*)&Ks[jl][sc] = hK;
            const float* vp = kp + 256;
            float4 vx = ((const float4*)vp)[0];
            float4 vy = ((const float4*)vp)[1];
            float vv[8] = {vx.x, vx.y, vx.z, vx.w, vy.x, vy.y, vy.z, vy.w};
            #pragma unroll
            for (int i = 0; i < 8; i++) Vt[sc + i][jl] = f2bf(vv[i]);
        }
        __syncthreads();

        f32x4 S[4];
        #pragma unroll
        for (int jt = 0; jt < 4; jt++) {
            bf16x8 kf = *(const bf16x8*)&Ks[jt * 16 + l16][hi * 8];
            S[jt] = __builtin_amdgcn_mfma_f32_16x16x32_bf16(qf, kf,
                     (f32x4){0.f, 0.f, 0.f, 0.f}, 0, 0, 0);
        }
        float cm[4] = {-1e30f, -1e30f, -1e30f, -1e30f};
        #pragma unroll
        for (int jt = 0; jt < 4; jt++) {
            bool ok = (c0 + jt * 16 + l16) < 300;
            #pragma unroll
            for (int r = 0; r < 4; r++) {
                float s = ok ? S[jt][r] : -1e30f;
                S[jt][r] = s;
                cm[r] = fmaxf(cm[r], s);
            }
        }
        #pragma unroll
        for (int o = 1; o < 16; o <<= 1)
            #pragma unroll
            for (int r = 0; r < 4; r++) cm[r] = fmaxf(cm[r], __shfl_xor(cm[r], o));
        float corr[4];
        #pragma unroll
        for (int r = 0; r < 4; r++) {
            float nm = fmaxf(m[r], cm[r]);
            corr[r] = __expf(m[r] - nm);
            m[r] = nm;
        }
        float ps[4] = {0.f, 0.f, 0.f, 0.f};
        #pragma unroll
        for (int jt = 0; jt < 4; jt++)
            #pragma unroll
            for (int r = 0; r < 4; r++) {
                float p = __expf(S[jt][r] - m[r]);
                S[jt][r] = p;
                ps[r] += p;
            }
        #pragma unroll
        for (int o = 1; o < 16; o <<= 1)
            #pragma unroll
            for (int r = 0; r < 4; r++) ps[r] += __shfl_xor(ps[r], o);
        #pragma unroll
        for (int r = 0; r < 4; r++) l[r] = l[r] * corr[r] + ps[r];
        #pragma unroll
        for (int r = 0; r < 4; r++) { acc0[r] *= corr[r]; acc1[r] *= corr[r]; }
        #pragma unroll
        for (int jt = 0; jt < 4; jt++)
            #pragma unroll
            for (int r = 0; r < 4; r++)
                Pl[w][(hi << 2) + r][jt * 16 + l16] = f2bf(S[jt][r]);
        #pragma unroll
        for (int half = 0; half < 2; half++) {
            bf16x8 pf = *(const bf16x8*)&Pl[w][l16][half * 32 + hi * 8];
            bf16x8 vf0 = *(const bf16x8*)&Vt[l16][half * 32 + hi * 8];
            bf16x8 vf1 = *(const bf16x8*)&Vt[16 + l16][half * 32 + hi * 8];
            acc0 = __builtin_amdgcn_mfma_f32_16x16x32_bf16(pf, vf0, acc0, 0, 0, 0);
            acc1 = __builtin_amdgcn_mfma_f32_16x16x32_bf16(pf, vf1, acc1, 0, 0, 0);
        }
    }
    #pragma unroll
    for (int r = 0; r < 4; r++) {
        int q = q0 + (w << 4) + (hi << 2) + r;
        if (q < 300) {
            float inv = 1.f / l[r];
            float* op = AO + ((size_t)(b * 300 + q) * 17 + kslot) * 256 + h * 32;
            op[l16] = acc0[r] * inv;
            op[16 + l16] = acc1[r] * inv;
        }
    }
}

// ---------------- MSDeformAttn sampling, two-phase ----------------
__global__ __launch_bounds__(256) void k_msda(const float* __restrict__ OFF,
                                              const float* __restrict__ AWL,
                                              const float* __restrict__ REF,
                                              const float* __restrict__ VAL,
                                              float* __restrict__ OUT) {
    __shared__ int   sIdx[128][4];
    __shared__ float sWgt[128][4];
    const int Hs[4] = {92, 46, 23, 12};
    const int starts[4] = {0, 8464, 10580, 11109};
    int rowq = blockIdx.x;
    int b = rowq / 5100;
    int tid = threadIdx.x;

    if (tid < 128) {
        int h = tid >> 4, p = tid & 15;
        float logit = AWL[(size_t)rowq * 128 + h * 16 + p];
        float mx = logit;
        #pragma unroll
        for (int o = 1; o < 16; o <<= 1) mx = fmaxf(mx, __shfl_xor(mx, o));
        float e = __expf(logit - mx);
        float ssum = e;
        #pragma unroll
        for (int o = 1; o < 16; o <<= 1) ssum += __shfl_xor(ssum, o);
        float aw = e / ssum;

        int l = p >> 2;
        int Ww = Hs[l];
        float fw = (float)Ww;
        float rx = REF[(size_t)rowq * 8 + l * 2];
        float ry = REF[(size_t)rowq * 8 + l * 2 + 1];
        float ox = OFF[(size_t)rowq * 256 + h * 32 + p * 2];
        float oy = OFF[(size_t)rowq * 256 + h * 32 + p * 2 + 1];
        float x = (rx + ox / fw) * fw - 0.5f;
        float y = (ry + oy / fw) * fw - 0.5f;
        float x0f = floorf(x), y0f = floorf(y);
        float wx = x - x0f, wy = y - y0f;
        int x0 = (int)x0f, y0 = (int)y0f;
        bool xv0 = (x0 >= 0) & (x0 < Ww), xv1 = (x0 + 1 >= 0) & (x0 + 1 < Ww);
        bool yv0 = (y0 >= 0) & (y0 < Ww), yv1 = (y0 + 1 >= 0) & (y0 + 1 < Ww);
        int x0c = min(max(x0, 0), Ww - 1), x1c = min(max(x0 + 1, 0), Ww - 1);
        int y0c = min(max(y0, 0), Ww - 1), y1c = min(max(y0 + 1, 0), Ww - 1);
        int base = b * LVV + starts[l];
        sIdx[tid][0] = base + y0c * Ww + x0c;
        sIdx[tid][1] = base + y0c * Ww + x1c;
        sIdx[tid][2] = base + y1c * Ww + x0c;
        sIdx[tid][3] = base + y1c * Ww + x1c;
        sWgt[tid][0] = (yv0 && xv0) ? (1.f - wx) * (1.f - wy) * aw : 0.f;
        sWgt[tid][1] = (yv0 && xv1) ? wx * (1.f - wy) * aw : 0.f;
        sWgt[tid][2] = (yv1 && xv0) ? (1.f - wx) * wy * aw : 0.f;
        sWgt[tid][3] = (yv1 && xv1) ? wx * wy * aw : 0.f;
    }
    __syncthreads();

    int h = tid >> 5, hd = tid & 31;
    int off = h * 32 + hd;
    float out = 0.f;
    #pragma unroll
    for (int p = 0; p < 16; p++) {
        int mI = h * 16 + p;
        int i0 = sIdx[mI][0], i1 = sIdx[mI][1], i2 = sIdx[mI][2], i3 = sIdx[mI][3];
        float w0 = sWgt[mI][0], w1 = sWgt[mI][1], w2 = sWgt[mI][2], w3 = sWgt[mI][3];
        out += w0 * VAL[(size_t)i0 * 256 + off]
             + w1 * VAL[(size_t)i1 * 256 + off]
             + w2 * VAL[(size_t)i2 * 256 + off]
             + w3 * VAL[(size_t)i3 * 256 + off];
    }
    OUT[(size_t)rowq * 256 + off] = out;
}

// ---------------- launch ----------------
extern "C" void kernel_launch(void* const* d_in, const int* in_sizes, int n_in,
                              void* d_out, int out_size, void* d_ws, size_t ws_size,
                              hipStream_t stream) {
    const float* tgt     = (const float*)d_in[0];
    const float* pos     = (const float*)d_in[1];
    const float* refpts  = (const float*)d_in[2];
    const float* memory  = (const float*)d_in[3];
    const float* wa_in_w  = (const float*)d_in[5];
    const float* wa_in_b  = (const float*)d_in[6];
    const float* wa_out_w = (const float*)d_in[7];
    const float* wa_out_b = (const float*)d_in[8];
    const float* ac_in_w  = (const float*)d_in[9];
    const float* ac_in_b  = (const float*)d_in[10];
    const float* ac_out_w = (const float*)d_in[11];
    const float* ac_out_b = (const float*)d_in[12];
    const float* ms_val_w = (const float*)d_in[13];
    const float* ms_val_b = (const float*)d_in[14];
    const float* ms_off_w = (const float*)d_in[15];
    const float* ms_off_b = (const float*)d_in[16];
    const float* ms_aw_w  = (const float*)d_in[17];
    const float* ms_aw_b  = (const float*)d_in[18];
    const float* ms_out_w = (const float*)d_in[19];
    const float* ms_out_b = (const float*)d_in[20];
    const float* gate_w   = (const float*)d_in[21];
    const float* gate_b   = (const float*)d_in[22];
    const float* l1_w     = (const float*)d_in[23];
    const float* l1_b     = (const float*)d_in[24];
    const float* l2_w     = (const float*)d_in[25];
    const float* l2_b     = (const float*)d_in[26];
    const float* gn_g     = (const float*)d_in[27];
    const float* wn_g     = (const float*)d_in[28];
    const float* an_g     = (const float*)d_in[29];
    const float* n2_g     = (const float*)d_in[30];
    const float* gn_b     = (const float*)d_in[31];
    const float* wn_b     = (const float*)d_in[32];
    const float* an_b     = (const float*)d_in[33];
    const float* n2_b     = (const float*)d_in[34];

    float* ws = (float*)d_ws;
    const size_t SROW = (size_t)NROW * 256;   // floats per 20400x256 tensor
    float* TP  = ws;
    float* Qb  = ws + SROW;
    float* T2  = ws + 2 * SROW;
    float* BIG = ws + 3 * SROW;               // 20400 x 1024 scratch
    float* OFF = BIG;                                     // 20400 x 256
    float* AW  = BIG + SROW;                              // 20400 x 128
    float* VAL = BIG + (size_t)NROW * 384;                // 45012 x 256
    float* GI    = BIG;                                   // 20400 x 512
    float* GATES = BIG + (size_t)NROW * 512;              // 20400 x 512
    float* Xb  = (float*)d_out;

    const int n4 = NROW * 64;
    const int gx = (NROW + 127) / 128;          // 160
    const int gxv = (BSZ * LVV + 127) / 128;    // 352

    // 1. TP = tgt + pos
    k_add<<<(n4 + 255) / 256, 256, 0, stream>>>((const float4*)tgt, (const float4*)pos, (float4*)TP, n4);
    // 2. wa QKV
    k_gemm_mfma<0><<<dim3(gx, 6), 256, 0, stream>>>(TP, wa_in_w, wa_in_b, BIG, NROW, 768, 256);
    // 3. within-attn
    k_wattn<<<1200 * 8, 64, 0, stream>>>(BIG, T2);
    // 4. wa out proj
    k_gemm_mfma<0><<<dim3(gx, 2), 256, 0, stream>>>(T2, wa_out_w, wa_out_b, Xb, NROW, 256, 256);
    // 5. TP = LN(TP + Xb; wn)
    k_ln_res<<<(NROW + 3) / 4, 256, 0, stream>>>(TP, Xb, wn_g, wn_b, TP, NROW);
    // 6. ac QKV
    k_gemm_mfma<0><<<dim3(gx, 6), 256, 0, stream>>>(TP, ac_in_w, ac_in_b, BIG, NROW, 768, 256);
    // 7. across-attn (MFMA flash)
    k_acattn_mfma<<<68 * 8 * 5, 256, 0, stream>>>(BIG, T2);
    // 8. ac out proj
    k_gemm_mfma<0><<<dim3(gx, 2), 256, 0, stream>>>(T2, ac_out_w, ac_out_b, Xb, NROW, 256, 256);
    // 9. TP = LN(TP + Xb; an)
    k_ln_res<<<(NROW + 3) / 4, 256, 0, stream>>>(TP, Xb, an_g, an_b, TP, NROW);
    // 10. Q = TP + pos
    k_add<<<(n4 + 255) / 256, 256, 0, stream>>>((const float4*)TP, (const float4*)pos, (float4*)Qb, n4);
    // 11. val = memory @ ms_val_w.T + b  (into BIG tail)
    k_gemm_mfma<0><<<dim3(gxv, 2), 256, 0, stream>>>(memory, ms_val_w, ms_val_b, VAL, BSZ * LVV, 256, 256);
    // 12. off
    k_gemm_mfma<0><<<dim3(gx, 2), 256, 0, stream>>>(Qb, ms_off_w, ms_off_b, OFF, NROW, 256, 256);
    // 13. aw logits
    k_gemm_mfma<0><<<dim3(gx, 1), 256, 0, stream>>>(Qb, ms_aw_w, ms_aw_b, AW, NROW, 128, 256);
    // 14. sample -> TP
    k_msda<<<NROW, 256, 0, stream>>>(OFF, AW, refpts, VAL, TP);
    // 15. ms out proj
    k_gemm_mfma<0><<<dim3(gx, 2), 256, 0, stream>>>(TP, ms_out_w, ms_out_b, T2, NROW, 256, 256);
    // 16. gi = [Q | T2]
    k_concat<<<(NROW * 128 + 255) / 256, 256, 0, stream>>>((const float4*)Qb, (const float4*)T2, (float4*)GI, NROW);
    // 17. gates = sigmoid(gi @ gate_w.T + b)
    k_gemm_mfma<2><<<dim3(gx, 4), 256, 0, stream>>>(GI, gate_w, gate_b, GATES, NROW, 512, 512);
    // 18. x = LN(g1*Q + g2*T2; gn) -> Xb
    k_ln_gate<<<(NROW + 3) / 4, 256, 0, stream>>>(GATES, Qb, T2, gn_g, gn_b, Xb, NROW);
    // 19. f1 = relu(x @ l1.T + b)
    k_gemm_mfma<1><<<dim3(gx, 8), 256, 0, stream>>>(Xb, l1_w, l1_b, BIG, NROW, 1024, 256);
    // 20. f = f1 @ l2.T + b
    k_gemm_mfma<0><<<dim3(gx, 2), 256, 0, stream>>>(BIG, l2_w, l2_b, T2, NROW, 256, 1024);
    // 21. out = LN(x + f; n2)
    k_ln_res<<<(NROW + 3) / 4, 256, 0, stream>>>(Xb, T2, n2_g, n2_b, (float*)d_out, NROW);
}

// Round 13
// 681.702 us; speedup vs baseline: 1.8197x; 1.2303x over previous
//
#include <hip/hip_runtime.h>
#include <math.h>

// ---------------- problem constants ----------------
#define DD   256
#define NHH  8
#define HDIM 32
#define BSZ  4
#define NQQ  300
#define NKK  17
#define LQQ  (NQQ*NKK)      // 5100
#define NROW (BSZ*LQQ)      // 20400
#define LVV  11253

typedef __attribute__((ext_vector_type(8))) short bf16x8;
typedef __attribute__((ext_vector_type(4))) short b16x4;
typedef __attribute__((ext_vector_type(4))) float f32x4;

__device__ __forceinline__ unsigned short f2bf(float f) {
    unsigned int u = __float_as_uint(f);
    u = u + 0x7FFFu + ((u >> 16) & 1u);   // RNE
    return (unsigned short)(u >> 16);
}
__device__ __forceinline__ float b2f(unsigned short u) {
    return __uint_as_float((unsigned int)u << 16);
}

// ---------------- weight pre-convert: 11 fp32 arrays -> concatenated bf16 ----------------
__global__ __launch_bounds__(256) void k_wcvt(const float* __restrict__ wa_in, const float* __restrict__ wa_out,
                                              const float* __restrict__ ac_in, const float* __restrict__ ac_out,
                                              const float* __restrict__ ms_val, const float* __restrict__ ms_off,
                                              const float* __restrict__ ms_aw, const float* __restrict__ ms_out,
                                              const float* __restrict__ gate, const float* __restrict__ l1,
                                              const float* __restrict__ l2, unsigned short* __restrict__ W16) {
    size_t idx = ((size_t)blockIdx.x * 256 + threadIdx.x) * 8;
    if (idx >= 1540096) return;
    const float* src; size_t loc;
    if      (idx <  196608) { src = wa_in;  loc = idx; }
    else if (idx <  262144) { src = wa_out; loc = idx -  196608; }
    else if (idx <  458752) { src = ac_in;  loc = idx -  262144; }
    else if (idx <  524288) { src = ac_out; loc = idx -  458752; }
    else if (idx <  589824) { src = ms_val; loc = idx -  524288; }
    else if (idx <  655360) { src = ms_off; loc = idx -  589824; }
    else if (idx <  688128) { src = ms_aw;  loc = idx -  655360; }
    else if (idx <  753664) { src = ms_out; loc = idx -  688128; }
    else if (idx < 1015808) { src = gate;   loc = idx -  753664; }
    else if (idx < 1277952) { src = l1;     loc = idx - 1015808; }
    else                    { src = l2;     loc = idx - 1277952; }
    float4 x = ((const float4*)(src + loc))[0];
    float4 y = ((const float4*)(src + loc))[1];
    float v[8] = {x.x, x.y, x.z, x.w, y.x, y.y, y.z, y.w};
    bf16x8 h;
    #pragma unroll
    for (int i = 0; i < 8; i++) h[i] = (short)f2bf(v[i]);
    *(bf16x8*)(W16 + idx) = h;
}

// ---------------- add: fp32+fp32 -> fp32 + bf16 (8 floats/thread) ----------------
__global__ __launch_bounds__(256) void k_add_dw(const float4* __restrict__ a, const float4* __restrict__ b,
                                                float4* __restrict__ o32, unsigned short* __restrict__ o16, int n8) {
    int i = blockIdx.x * 256 + threadIdx.x;
    if (i >= n8) return;
    float4 x0 = a[i * 2], y0 = b[i * 2];
    float4 x1 = a[i * 2 + 1], y1 = b[i * 2 + 1];
    float4 s0 = make_float4(x0.x + y0.x, x0.y + y0.y, x0.z + y0.z, x0.w + y0.w);
    float4 s1 = make_float4(x1.x + y1.x, x1.y + y1.y, x1.z + y1.z, x1.w + y1.w);
    o32[i * 2] = s0; o32[i * 2 + 1] = s1;
    bf16x8 h;
    h[0]=(short)f2bf(s0.x); h[1]=(short)f2bf(s0.y); h[2]=(short)f2bf(s0.z); h[3]=(short)f2bf(s0.w);
    h[4]=(short)f2bf(s1.x); h[5]=(short)f2bf(s1.y); h[6]=(short)f2bf(s1.z); h[7]=(short)f2bf(s1.w);
    *(bf16x8*)(o16 + (size_t)i * 8) = h;
}

// ---------------- add: fp32+fp32 -> bf16 only ----------------
__global__ __launch_bounds__(256) void k_add_b16(const float4* __restrict__ a, const float4* __restrict__ b,
                                                 unsigned short* __restrict__ o16, int n8) {
    int i = blockIdx.x * 256 + threadIdx.x;
    if (i >= n8) return;
    float4 x0 = a[i * 2], y0 = b[i * 2];
    float4 x1 = a[i * 2 + 1], y1 = b[i * 2 + 1];
    bf16x8 h;
    h[0]=(short)f2bf(x0.x+y0.x); h[1]=(short)f2bf(x0.y+y0.y); h[2]=(short)f2bf(x0.z+y0.z); h[3]=(short)f2bf(x0.w+y0.w);
    h[4]=(short)f2bf(x1.x+y1.x); h[5]=(short)f2bf(x1.y+y1.y); h[6]=(short)f2bf(x1.z+y1.z); h[7]=(short)f2bf(x1.w+y1.w);
    *(bf16x8*)(o16 + (size_t)i * 8) = h;
}

// ---------------- concat bf16 [Q | T2] -> 512-wide ----------------
__global__ __launch_bounds__(256) void k_concat16(const unsigned short* __restrict__ a,
                                                  const unsigned short* __restrict__ b,
                                                  unsigned short* __restrict__ o, int rows) {
    int i = blockIdx.x * 256 + threadIdx.x;   // 8-short chunks; rows*64 total
    if (i >= rows * 64) return;
    int r = i >> 6, c8 = i & 63;
    const unsigned short* src = (c8 < 32) ? (a + (size_t)r * 256 + c8 * 8)
                                          : (b + (size_t)r * 256 + (c8 - 32) * 8);
    *(bf16x8*)(o + (size_t)r * 512 + c8 * 8) = *(const bf16x8*)src;
}

// ---------------- MFMA GEMM 128x128: C = act(A @ B^T + bias) ----------------
// A: M x K bf16 (or fp32 if A32); B: N x K bf16 (pre-converted weights).
// OMODE bit0: write C32 fp32; bit1: write C16 bf16.
template<int ACT, int OMODE, bool A32>
__global__ __launch_bounds__(256) void k_gemm_mfma(const void* __restrict__ Av,
                                                   const unsigned short* __restrict__ B,
                                                   const float* __restrict__ bias,
                                                   float* __restrict__ C32,
                                                   unsigned short* __restrict__ C16,
                                                   int M, int N, int K) {
    __shared__ unsigned short As[128][40];
    __shared__ unsigned short Bs[128][40];
    int t = threadIdx.x;
    int lane = t & 63, w = t >> 6;
    int l16 = lane & 15, hi = lane >> 4;
    int wr = (w >> 1) << 6, wc = (w & 1) << 6;
    int row0 = blockIdx.x * 128, col0 = blockIdx.y * 128;
    int srow = t >> 2;
    int scol = (t & 3) * 8;

    f32x4 acc[4][4];
    #pragma unroll
    for (int m = 0; m < 4; m++)
        #pragma unroll
        for (int n = 0; n < 4; n++) acc[m][n] = (f32x4){0.f, 0.f, 0.f, 0.f};

    for (int k0 = 0; k0 < K; k0 += 32) {
        #pragma unroll
        for (int half = 0; half < 2; half++) {
            int r = srow + half * 64;
            int gr = row0 + r;
            if (A32) {
                const float* A = (const float*)Av;
                float v[8];
                if (gr < M) {
                    const float4* p = (const float4*)(A + (size_t)gr * K + k0 + scol);
                    float4 x = p[0], y = p[1];
                    v[0]=x.x; v[1]=x.y; v[2]=x.z; v[3]=x.w; v[4]=y.x; v[5]=y.y; v[6]=y.z; v[7]=y.w;
                } else {
                    #pragma unroll
                    for (int i = 0; i < 8; i++) v[i] = 0.f;
                }
                bf16x8 hh;
                #pragma unroll
                for (int i = 0; i < 8; i++) hh[i] = (short)f2bf(v[i]);
                *(bf16x8*)&As[r][scol] = hh;
            } else {
                const unsigned short* A = (const unsigned short*)Av;
                bf16x8 hh;
                if (gr < M) hh = *(const bf16x8*)(A + (size_t)gr * K + k0 + scol);
                else        hh = (bf16x8){0,0,0,0,0,0,0,0};
                *(bf16x8*)&As[r][scol] = hh;
            }
            int gb = col0 + r;   // always < N (N % 128 == 0)
            *(bf16x8*)&Bs[r][scol] = *(const bf16x8*)(B + (size_t)gb * K + k0 + scol);
        }
        __syncthreads();
        bf16x8 af[4], bfr[4];
        #pragma unroll
        for (int m = 0; m < 4; m++) af[m] = *(const bf16x8*)&As[wr + m * 16 + l16][hi * 8];
        #pragma unroll
        for (int n = 0; n < 4; n++) bfr[n] = *(const bf16x8*)&Bs[wc + n * 16 + l16][hi * 8];
        #pragma unroll
        for (int m = 0; m < 4; m++)
            #pragma unroll
            for (int n = 0; n < 4; n++)
                acc[m][n] = __builtin_amdgcn_mfma_f32_16x16x32_bf16(af[m], bfr[n], acc[m][n], 0, 0, 0);
        __syncthreads();
    }
    #pragma unroll
    for (int n = 0; n < 4; n++) {
        int col = col0 + wc + n * 16 + l16;
        float bv = bias[col];
        #pragma unroll
        for (int m = 0; m < 4; m++) {
            #pragma unroll
            for (int r = 0; r < 4; r++) {
                int row = row0 + wr + m * 16 + (hi << 2) + r;
                if (row < M) {
                    float v = acc[m][n][r] + bv;
                    if (ACT == 1) v = fmaxf(v, 0.f);
                    else if (ACT == 2) v = 1.f / (1.f + __expf(-v));
                    if (OMODE & 1) C32[(size_t)row * N + col] = v;
                    if (OMODE & 2) C16[(size_t)row * N + col] = f2bf(v);
                }
            }
        }
    }
}

// ---------------- LayerNorm(a + b) * g + beta (fp32 in), optional bf16 dual-out ----------------
template<bool DUAL>
__global__ __launch_bounds__(256) void k_ln_res(const float* __restrict__ A,
                                                const float* __restrict__ Bp,
                                                const float* __restrict__ g,
                                                const float* __restrict__ be,
                                                float* __restrict__ O,
                                                unsigned short* __restrict__ O16, int M) {
    int row = blockIdx.x * 4 + (threadIdx.x >> 6);
    int lane = threadIdx.x & 63;
    if (row >= M) return;
    float4 a = ((const float4*)A)[(size_t)row * 64 + lane];
    float4 b = ((const float4*)Bp)[(size_t)row * 64 + lane];
    float x0 = a.x + b.x, x1 = a.y + b.y, x2 = a.z + b.z, x3 = a.w + b.w;
    float s = x0 + x1 + x2 + x3;
    float sq = x0 * x0 + x1 * x1 + x2 * x2 + x3 * x3;
    #pragma unroll
    for (int o = 32; o; o >>= 1) { s += __shfl_xor(s, o); sq += __shfl_xor(sq, o); }
    float mean = s * (1.f / 256.f);
    float var = sq * (1.f / 256.f) - mean * mean;
    float rs = rsqrtf(var + 1e-5f);
    float4 gg = ((const float4*)g)[lane];
    float4 bb = ((const float4*)be)[lane];
    float4 o4;
    o4.x = (x0 - mean) * rs * gg.x + bb.x;
    o4.y = (x1 - mean) * rs * gg.y + bb.y;
    o4.z = (x2 - mean) * rs * gg.z + bb.z;
    o4.w = (x3 - mean) * rs * gg.w + bb.w;
    ((float4*)O)[(size_t)row * 64 + lane] = o4;
    if (DUAL) {
        b16x4 h;
        h[0]=(short)f2bf(o4.x); h[1]=(short)f2bf(o4.y); h[2]=(short)f2bf(o4.z); h[3]=(short)f2bf(o4.w);
        *(b16x4*)(O16 + (size_t)row * 256 + lane * 4) = h;
    }
}

// ---------------- gated LayerNorm: bf16 gates/Q/T2 in -> fp32 + bf16 out ----------------
__global__ __launch_bounds__(256) void k_ln_gate_b(const unsigned short* __restrict__ G,
                                                   const unsigned short* __restrict__ Q,
                                                   const unsigned short* __restrict__ T2,
                                                   const float* __restrict__ g,
                                                   const float* __restrict__ be,
                                                   float* __restrict__ O,
                                                   unsigned short* __restrict__ O16, int M) {
    int row = blockIdx.x * 4 + (threadIdx.x >> 6);
    int lane = threadIdx.x & 63;
    if (row >= M) return;
    b16x4 g1 = *(const b16x4*)(G + (size_t)row * 512 + lane * 4);
    b16x4 g2 = *(const b16x4*)(G + (size_t)row * 512 + 256 + lane * 4);
    b16x4 q  = *(const b16x4*)(Q + (size_t)row * 256 + lane * 4);
    b16x4 tt = *(const b16x4*)(T2 + (size_t)row * 256 + lane * 4);
    float x0 = b2f((unsigned short)g1[0]) * b2f((unsigned short)q[0]) + b2f((unsigned short)g2[0]) * b2f((unsigned short)tt[0]);
    float x1 = b2f((unsigned short)g1[1]) * b2f((unsigned short)q[1]) + b2f((unsigned short)g2[1]) * b2f((unsigned short)tt[1]);
    float x2 = b2f((unsigned short)g1[2]) * b2f((unsigned short)q[2]) + b2f((unsigned short)g2[2]) * b2f((unsigned short)tt[2]);
    float x3 = b2f((unsigned short)g1[3]) * b2f((unsigned short)q[3]) + b2f((unsigned short)g2[3]) * b2f((unsigned short)tt[3]);
    float s = x0 + x1 + x2 + x3;
    float sq = x0 * x0 + x1 * x1 + x2 * x2 + x3 * x3;
    #pragma unroll
    for (int o = 32; o; o >>= 1) { s += __shfl_xor(s, o); sq += __shfl_xor(sq, o); }
    float mean = s * (1.f / 256.f);
    float var = sq * (1.f / 256.f) - mean * mean;
    float rs = rsqrtf(var + 1e-5f);
    float4 gg = ((const float4*)g)[lane];
    float4 bb = ((const float4*)be)[lane];
    float4 o4;
    o4.x = (x0 - mean) * rs * gg.x + bb.x;
    o4.y = (x1 - mean) * rs * gg.y + bb.y;
    o4.z = (x2 - mean) * rs * gg.z + bb.z;
    o4.w = (x3 - mean) * rs * gg.w + bb.w;
    ((float4*)O)[(size_t)row * 64 + lane] = o4;
    b16x4 h;
    h[0]=(short)f2bf(o4.x); h[1]=(short)f2bf(o4.y); h[2]=(short)f2bf(o4.z); h[3]=(short)f2bf(o4.w);
    *(b16x4*)(O16 + (size_t)row * 256 + lane * 4) = h;
}

// ---------------- within-group attention (17 tokens), bf16 QKV in, bf16 out ----------------
__global__ __launch_bounds__(64) void k_wattn_b(const unsigned short* __restrict__ QKV,
                                                unsigned short* __restrict__ AO) {
    int unit = blockIdx.x;
    int h = unit & 7;
    int sqc = unit >> 3;
    int lane = threadIdx.x;
    __shared__ float q[17][32], kk[17][32], vv[17][32], sc[17][17];
    for (int idx = lane; idx < 17 * 32; idx += 64) {
        int r = idx >> 5, c = idx & 31;
        const unsigned short* base = QKV + (size_t)(sqc * 17 + r) * 768 + h * 32 + c;
        q[r][c] = b2f(base[0]);
        kk[r][c] = b2f(base[256]);
        vv[r][c] = b2f(base[512]);
    }
    __syncthreads();
    const float scale = 0.17677669529663687f;
    for (int idx = lane; idx < 289; idx += 64) {
        int i = idx / 17, j = idx % 17;
        float d = 0.f;
        #pragma unroll
        for (int c = 0; c < 32; c++) d += q[i][c] * kk[j][c];
        sc[i][j] = d * scale;
    }
    __syncthreads();
    if (lane < 17) {
        float mm = -1e30f;
        for (int j = 0; j < 17; j++) mm = fmaxf(mm, sc[lane][j]);
        float ss = 0.f;
        for (int j = 0; j < 17; j++) { float e = __expf(sc[lane][j] - mm); sc[lane][j] = e; ss += e; }
        float iv = 1.f / ss;
        for (int j = 0; j < 17; j++) sc[lane][j] *= iv;
    }
    __syncthreads();
    for (int idx = lane; idx < 17 * 32; idx += 64) {
        int i = idx >> 5, c = idx & 31;
        float o = 0.f;
        #pragma unroll
        for (int j = 0; j < 17; j++) o += sc[i][j] * vv[j][c];
        AO[(size_t)(sqc * 17 + i) * 256 + h * 32 + c] = f2bf(o);
    }
}

// ---------------- across-group attention MFMA flash, bf16 QKV in, bf16 out ----------------
__global__ __launch_bounds__(256) void k_acattn_mfma_b(const unsigned short* __restrict__ QKV,
                                                       unsigned short* __restrict__ AO) {
    __shared__ unsigned short Ks[64][40];
    __shared__ unsigned short Vt[32][66];
    __shared__ unsigned short Pl[4][16][72];

    int blk = blockIdx.x;
    int qb = blk % 5;
    int rest = blk / 5;
    int h = rest & 7;
    int bk = rest >> 3;
    int kslot = bk % 17;
    int b = bk / 17;

    int t = threadIdx.x;
    int lane = t & 63, w = t >> 6;
    int l16 = lane & 15, hi = lane >> 4;
    const float scale = 0.17677669529663687f;

    int q0 = qb * 64;
    int qrow = q0 + (w << 4) + l16;
    int qc = qrow < 300 ? qrow : 299;
    bf16x8 qf = *(const bf16x8*)(QKV + ((size_t)(b * 300 + qc) * 17 + kslot) * 768 + h * 32 + hi * 8);

    f32x4 acc0 = (f32x4){0.f, 0.f, 0.f, 0.f};
    f32x4 acc1 = (f32x4){0.f, 0.f, 0.f, 0.f};
    float m[4], l[4];
    #pragma unroll
    for (int r = 0; r < 4; r++) { m[r] = -1e30f; l[r] = 0.f; }

    int jl = t >> 2;
    int sc = (t & 3) * 8;

    for (int c0 = 0; c0 < 300; c0 += 64) {
        __syncthreads();
        {
            int krow = c0 + jl; if (krow > 299) krow = 299;
            const unsigned short* kp = QKV + ((size_t)(b * 300 + krow) * 17 + kslot) * 768 + 256 + h * 32 + sc;
            *(bf16x8*)&Ks[jl][sc] = *(const bf16x8*)kp;
            bf16x8 vv = *(const bf16x8*)(kp + 256);
            #pragma unroll
            for (int i = 0; i < 8; i++) Vt[sc + i][jl] = (unsigned short)vv[i];
        }
        __syncthreads();

        f32x4 S[4];
        #pragma unroll
        for (int jt = 0; jt < 4; jt++) {
            bf16x8 kf = *(const bf16x8*)&Ks[jt * 16 + l16][hi * 8];
            S[jt] = __builtin_amdgcn_mfma_f32_16x16x32_bf16(qf, kf,
                     (f32x4){0.f, 0.f, 0.f, 0.f}, 0, 0, 0);
        }
        float cm[4] = {-1e30f, -1e30f, -1e30f, -1e30f};
        #pragma unroll
        for (int jt = 0; jt < 4; jt++) {
            bool ok = (c0 + jt * 16 + l16) < 300;
            #pragma unroll
            for (int r = 0; r < 4; r++) {
                float s = ok ? S[jt][r] * scale : -1e30f;
                S[jt][r] = s;
                cm[r] = fmaxf(cm[r], s);
            }
        }
        #pragma unroll
        for (int o = 1; o < 16; o <<= 1)
            #pragma unroll
            for (int r = 0; r < 4; r++) cm[r] = fmaxf(cm[r], __shfl_xor(cm[r], o));
        float corr[4];
        #pragma unroll
        for (int r = 0; r < 4; r++) {
            float nm = fmaxf(m[r], cm[r]);
            corr[r] = __expf(m[r] - nm);
            m[r] = nm;
        }
        float ps[4] = {0.f, 0.f, 0.f, 0.f};
        #pragma unroll
        for (int jt = 0; jt < 4; jt++)
            #pragma unroll
            for (int r = 0; r < 4; r++) {
                float p = __expf(S[jt][r] - m[r]);
                S[jt][r] = p;
                ps[r] += p;
            }
        #pragma unroll
        for (int o = 1; o < 16; o <<= 1)
            #pragma unroll
            for (int r = 0; r < 4; r++) ps[r] += __shfl_xor(ps[r], o);
        #pragma unroll
        for (int r = 0; r < 4; r++) l[r] = l[r] * corr[r] + ps[r];
        #pragma unroll
        for (int r = 0; r < 4; r++) { acc0[r] *= corr[r]; acc1[r] *= corr[r]; }
        #pragma unroll
        for (int jt = 0; jt < 4; jt++)
            #pragma unroll
            for (int r = 0; r < 4; r++)
                Pl[w][(hi << 2) + r][jt * 16 + l16] = f2bf(S[jt][r]);
        #pragma unroll
        for (int half = 0; half < 2; half++) {
            bf16x8 pf = *(const bf16x8*)&Pl[w][l16][half * 32 + hi * 8];
            bf16x8 vf0 = *(const bf16x8*)&Vt[l16][half * 32 + hi * 8];
            bf16x8 vf1 = *(const bf16x8*)&Vt[16 + l16][half * 32 + hi * 8];
            acc0 = __builtin_amdgcn_mfma_f32_16x16x32_bf16(pf, vf0, acc0, 0, 0, 0);
            acc1 = __builtin_amdgcn_mfma_f32_16x16x32_bf16(pf, vf1, acc1, 0, 0, 0);
        }
    }
    #pragma unroll
    for (int r = 0; r < 4; r++) {
        int q = q0 + (w << 4) + (hi << 2) + r;
        if (q < 300) {
            float inv = 1.f / l[r];
            unsigned short* op = AO + ((size_t)(b * 300 + q) * 17 + kslot) * 256 + h * 32;
            op[l16] = f2bf(acc0[r] * inv);
            op[16 + l16] = f2bf(acc1[r] * inv);
        }
    }
}

// ---------------- MSDeformAttn sampling, two-phase, bf16 in/out ----------------
__global__ __launch_bounds__(256) void k_msda_b(const unsigned short* __restrict__ OFF,
                                                const unsigned short* __restrict__ AWL,
                                                const float* __restrict__ REF,
                                                const unsigned short* __restrict__ VAL,
                                                unsigned short* __restrict__ OUT) {
    __shared__ int   sIdx[128][4];
    __shared__ float sWgt[128][4];
    const int Hs[4] = {92, 46, 23, 12};
    const int starts[4] = {0, 8464, 10580, 11109};
    int rowq = blockIdx.x;
    int b = rowq / 5100;
    int tid = threadIdx.x;

    if (tid < 128) {
        int h = tid >> 4, p = tid & 15;
        float logit = b2f(AWL[(size_t)rowq * 128 + h * 16 + p]);
        float mx = logit;
        #pragma unroll
        for (int o = 1; o < 16; o <<= 1) mx = fmaxf(mx, __shfl_xor(mx, o));
        float e = __expf(logit - mx);
        float ssum = e;
        #pragma unroll
        for (int o = 1; o < 16; o <<= 1) ssum += __shfl_xor(ssum, o);
        float aw = e / ssum;

        int l = p >> 2;
        int Ww = Hs[l];
        float fw = (float)Ww;
        float rx = REF[(size_t)rowq * 8 + l * 2];
        float ry = REF[(size_t)rowq * 8 + l * 2 + 1];
        float ox = b2f(OFF[(size_t)rowq * 256 + h * 32 + p * 2]);
        float oy = b2f(OFF[(size_t)rowq * 256 + h * 32 + p * 2 + 1]);
        float x = (rx + ox / fw) * fw - 0.5f;
        float y = (ry + oy / fw) * fw - 0.5f;
        float x0f = floorf(x), y0f = floorf(y);
        float wx = x - x0f, wy = y - y0f;
        int x0 = (int)x0f, y0 = (int)y0f;
        bool xv0 = (x0 >= 0) & (x0 < Ww), xv1 = (x0 + 1 >= 0) & (x0 + 1 < Ww);
        bool yv0 = (y0 >= 0) & (y0 < Ww), yv1 = (y0 + 1 >= 0) & (y0 + 1 < Ww);
        int x0c = min(max(x0, 0), Ww - 1), x1c = min(max(x0 + 1, 0), Ww - 1);
        int y0c = min(max(y0, 0), Ww - 1), y1c = min(max(y0 + 1, 0), Ww - 1);
        int base = b * LVV + starts[l];
        sIdx[tid][0] = base + y0c * Ww + x0c;
        sIdx[tid][1] = base + y0c * Ww + x1c;
        sIdx[tid][2] = base + y1c * Ww + x0c;
        sIdx[tid][3] = base + y1c * Ww + x1c;
        sWgt[tid][0] = (yv0 && xv0) ? (1.f - wx) * (1.f - wy) * aw : 0.f;
        sWgt[tid][1] = (yv0 && xv1) ? wx * (1.f - wy) * aw : 0.f;
        sWgt[tid][2] = (yv1 && xv0) ? (1.f - wx) * wy * aw : 0.f;
        sWgt[tid][3] = (yv1 && xv1) ? wx * wy * aw : 0.f;
    }
    __syncthreads();

    int h = tid >> 5, hd = tid & 31;
    int off = h * 32 + hd;
    float out = 0.f;
    #pragma unroll
    for (int p = 0; p < 16; p++) {
        int mI = h * 16 + p;
        int i0 = sIdx[mI][0], i1 = sIdx[mI][1], i2 = sIdx[mI][2], i3 = sIdx[mI][3];
        float w0 = sWgt[mI][0], w1 = sWgt[mI][1], w2 = sWgt[mI][2], w3 = sWgt[mI][3];
        out += w0 * b2f(VAL[(size_t)i0 * 256 + off])
             + w1 * b2f(VAL[(size_t)i1 * 256 + off])
             + w2 * b2f(VAL[(size_t)i2 * 256 + off])
             + w3 * b2f(VAL[(size_t)i3 * 256 + off]);
    }
    OUT[(size_t)rowq * 256 + off] = f2bf(out);
}

// ---------------- launch ----------------
extern "C" void kernel_launch(void* const* d_in, const int* in_sizes, int n_in,
                              void* d_out, int out_size, void* d_ws, size_t ws_size,
                              hipStream_t stream) {
    const float* tgt     = (const float*)d_in[0];
    const float* pos     = (const float*)d_in[1];
    const float* refpts  = (const float*)d_in[2];
    const float* memory  = (const float*)d_in[3];
    const float* wa_in_w  = (const float*)d_in[5];
    const float* wa_in_b  = (const float*)d_in[6];
    const float* wa_out_w = (const float*)d_in[7];
    const float* wa_out_b = (const float*)d_in[8];
    const float* ac_in_w  = (const float*)d_in[9];
    const float* ac_in_b  = (const float*)d_in[10];
    const float* ac_out_w = (const float*)d_in[11];
    const float* ac_out_b = (const float*)d_in[12];
    const float* ms_val_w = (const float*)d_in[13];
    const float* ms_val_b = (const float*)d_in[14];
    const float* ms_off_w = (const float*)d_in[15];
    const float* ms_off_b = (const float*)d_in[16];
    const float* ms_aw_w  = (const float*)d_in[17];
    const float* ms_aw_b  = (const float*)d_in[18];
    const float* ms_out_w = (const float*)d_in[19];
    const float* ms_out_b = (const float*)d_in[20];
    const float* gate_w   = (const float*)d_in[21];
    const float* gate_b   = (const float*)d_in[22];
    const float* l1_w     = (const float*)d_in[23];
    const float* l1_b     = (const float*)d_in[24];
    const float* l2_w     = (const float*)d_in[25];
    const float* l2_b     = (const float*)d_in[26];
    const float* gn_g     = (const float*)d_in[27];
    const float* wn_g     = (const float*)d_in[28];
    const float* an_g     = (const float*)d_in[29];
    const float* n2_g     = (const float*)d_in[30];
    const float* gn_b     = (const float*)d_in[31];
    const float* wn_b     = (const float*)d_in[32];
    const float* an_b     = (const float*)d_in[33];
    const float* n2_b     = (const float*)d_in[34];

    const size_t SROWF = (size_t)NROW * 256;      // 5,222,400 elems
    float* TP32 = (float*)d_ws;
    float* T232 = TP32 + SROWF;
    unsigned short* us0 = (unsigned short*)(TP32 + 2 * SROWF);
    unsigned short* OFF16 = us0;                          // 5,222,400
    unsigned short* AW16  = us0 + 5222400;                // 2,611,200
    unsigned short* TP16  = us0 + 7833600;                // 5,222,400
    unsigned short* T216  = us0 + 13056000;               // 5,222,400
    unsigned short* Qb16  = us0 + 18278400;               // 5,222,400
    unsigned short* X16   = us0 + 23500800;               // 5,222,400
    unsigned short* W16   = us0 + 28723200;               // 1,540,096
    unsigned short* SH    = us0 + 30263296;               // shared 20,889,600
    unsigned short* QKV16  = SH;                          // 20400x768
    unsigned short* VAL16  = SH;                          // 45012x256
    unsigned short* MS16   = SH + 12000000;               // 20400x256
    unsigned short* GI16   = SH;                          // 20400x512
    unsigned short* GATES16= SH + 10444800;               // 20400x512
    unsigned short* F116   = SH;                          // 20400x1024
    float* Xb32 = (float*)d_out;

    const unsigned short* W_wa_in  = W16;
    const unsigned short* W_wa_out = W16 + 196608;
    const unsigned short* W_ac_in  = W16 + 262144;
    const unsigned short* W_ac_out = W16 + 458752;
    const unsigned short* W_ms_val = W16 + 524288;
    const unsigned short* W_ms_off = W16 + 589824;
    const unsigned short* W_ms_aw  = W16 + 655360;
    const unsigned short* W_ms_out = W16 + 688128;
    const unsigned short* W_gate   = W16 + 753664;
    const unsigned short* W_l1     = W16 + 1015808;
    const unsigned short* W_l2     = W16 + 1277952;

    const int n8 = NROW * 32;                    // 8-float chunks of a 20400x256 tensor
    const int gx = (NROW + 127) / 128;           // 160
    const int gxv = (BSZ * LVV + 127) / 128;     // 352

    // 0. convert weights to bf16
    k_wcvt<<<753, 256, 0, stream>>>(wa_in_w, wa_out_w, ac_in_w, ac_out_w, ms_val_w, ms_off_w,
                                    ms_aw_w, ms_out_w, gate_w, l1_w, l2_w, W16);
    // 1. TP = tgt + pos (fp32 + bf16)
    k_add_dw<<<(n8 + 255) / 256, 256, 0, stream>>>((const float4*)tgt, (const float4*)pos, (float4*)TP32, TP16, n8);
    // 2. wa QKV (bf16 out)
    k_gemm_mfma<0, 2, false><<<dim3(gx, 6), 256, 0, stream>>>(TP16, W_wa_in, wa_in_b, nullptr, QKV16, NROW, 768, 256);
    // 3. within-attn
    k_wattn_b<<<1200 * 8, 64, 0, stream>>>(QKV16, T216);
    // 4. wa out proj (fp32 out)
    k_gemm_mfma<0, 1, false><<<dim3(gx, 2), 256, 0, stream>>>(T216, W_wa_out, wa_out_b, Xb32, nullptr, NROW, 256, 256);
    // 5. TP = LN(TP + Xb; wn) dual
    k_ln_res<true><<<(NROW + 3) / 4, 256, 0, stream>>>(TP32, Xb32, wn_g, wn_b, TP32, TP16, NROW);
    // 6. ac QKV
    k_gemm_mfma<0, 2, false><<<dim3(gx, 6), 256, 0, stream>>>(TP16, W_ac_in, ac_in_b, nullptr, QKV16, NROW, 768, 256);
    // 7. across-attn
    k_acattn_mfma_b<<<68 * 8 * 5, 256, 0, stream>>>(QKV16, T216);
    // 8. ac out proj
    k_gemm_mfma<0, 1, false><<<dim3(gx, 2), 256, 0, stream>>>(T216, W_ac_out, ac_out_b, Xb32, nullptr, NROW, 256, 256);
    // 9. TP = LN(TP + Xb; an) fp32 only
    k_ln_res<false><<<(NROW + 3) / 4, 256, 0, stream>>>(TP32, Xb32, an_g, an_b, TP32, nullptr, NROW);
    // 10. Qb = TP + pos (bf16)
    k_add_b16<<<(n8 + 255) / 256, 256, 0, stream>>>((const float4*)TP32, (const float4*)pos, Qb16, n8);
    // 11. val = memory @ ms_val.T (fp32 A, bf16 out)
    k_gemm_mfma<0, 2, true><<<dim3(gxv, 2), 256, 0, stream>>>(memory, W_ms_val, ms_val_b, nullptr, VAL16, BSZ * LVV, 256, 256);
    // 12. off (bf16 out)
    k_gemm_mfma<0, 2, false><<<dim3(gx, 2), 256, 0, stream>>>(Qb16, W_ms_off, ms_off_b, nullptr, OFF16, NROW, 256, 256);
    // 13. aw logits (bf16 out)
    k_gemm_mfma<0, 2, false><<<dim3(gx, 1), 256, 0, stream>>>(Qb16, W_ms_aw, ms_aw_b, nullptr, AW16, NROW, 128, 256);
    // 14. sample
    k_msda_b<<<NROW, 256, 0, stream>>>(OFF16, AW16, refpts, VAL16, MS16);
    // 15. ms out proj (bf16 out)
    k_gemm_mfma<0, 2, false><<<dim3(gx, 2), 256, 0, stream>>>(MS16, W_ms_out, ms_out_b, nullptr, T216, NROW, 256, 256);
    // 16. gi = [Qb | T2]
    k_concat16<<<(NROW * 64 + 255) / 256, 256, 0, stream>>>(Qb16, T216, GI16, NROW);
    // 17. gates = sigmoid(...) bf16
    k_gemm_mfma<2, 2, false><<<dim3(gx, 4), 256, 0, stream>>>(GI16, W_gate, gate_b, nullptr, GATES16, NROW, 512, 512);
    // 18. x = LN(g1*Qb + g2*T2; gn) -> Xb32 + X16
    k_ln_gate_b<<<(NROW + 3) / 4, 256, 0, stream>>>(GATES16, Qb16, T216, gn_g, gn_b, Xb32, X16, NROW);
    // 19. f1 = relu(x @ l1.T) bf16
    k_gemm_mfma<1, 2, false><<<dim3(gx, 8), 256, 0, stream>>>(X16, W_l1, l1_b, nullptr, F116, NROW, 1024, 256);
    // 20. f = f1 @ l2.T (fp32 out)
    k_gemm_mfma<0, 1, false><<<dim3(gx, 2), 256, 0, stream>>>(F116, W_l2, l2_b, T232, nullptr, NROW, 256, 1024);
    // 21. out = LN(x + f; n2)
    k_ln_res<false><<<(NROW + 3) / 4, 256, 0, stream>>>(Xb32, T232, n2_g, n2_b, (float*)d_out, nullptr, NROW);
}